// Round 3
// baseline (1432.286 us; speedup 1.0000x reference)
//
#include <hip/hip_runtime.h>

#define Nn 4096
#define Dd 512
#define Ee 65536
#define HOPS 10
#define TPB 512
#define RPT (Nn / TPB)  // 8 rows per thread
#define CT 4            // columns per block
#define WCAP 64         // ELL slot capacity (max in-degree+1; Poisson(16) max ~38)

// ---------------- sq[i] = sum_d w_d * x[i,d]^2 ----------------
__global__ __launch_bounds__(256) void k_sq(const float* __restrict__ x,
                                            const float* __restrict__ w,
                                            float* __restrict__ sq) {
  int row = blockIdx.x;
  int tid = threadIdx.x;
  const float* xr = x + (size_t)row * Dd;
  float partial = 0.f;
  for (int d = tid; d < Dd; d += 256) {
    float xv = xr[d];
    partial += xv * xv * w[d];
  }
  for (int off = 32; off >= 1; off >>= 1) partial += __shfl_down(partial, off, 64);
  __shared__ float red[4];
  int wv = tid >> 6, ln = tid & 63;
  if (ln == 0) red[wv] = partial;
  __syncthreads();
  if (tid == 0) sq[row] = red[0] + red[1] + red[2] + red[3];
}

// ---------------- K = sq_i + sq_j - 2 * (x*w) @ x^T ; diag -> 1 ----------------
__global__ __launch_bounds__(256) void k_gemm(const float* __restrict__ X,
                                              const float* __restrict__ w,
                                              const float* __restrict__ sq,
                                              float* __restrict__ C) {
  __shared__ float As[8][128];
  __shared__ float Bs[8][128];
  int i0 = blockIdx.y * 128, j0 = blockIdx.x * 128;
  int tid = threadIdx.x;
  int ty = tid >> 4, tx = tid & 15;
  int lr = tid >> 1, lk = (tid & 1) * 4;
  float acc[8][8];
#pragma unroll
  for (int a = 0; a < 8; a++)
#pragma unroll
    for (int b = 0; b < 8; b++) acc[a][b] = 0.f;

  for (int k0 = 0; k0 < Dd; k0 += 8) {
    float4 wv4 = *(const float4*)&w[k0 + lk];
    float4 av4 = *(const float4*)&X[(size_t)(i0 + lr) * Dd + k0 + lk];
    float4 bv4 = *(const float4*)&X[(size_t)(j0 + lr) * Dd + k0 + lk];
    As[lk + 0][lr] = av4.x * wv4.x; As[lk + 1][lr] = av4.y * wv4.y;
    As[lk + 2][lr] = av4.z * wv4.z; As[lk + 3][lr] = av4.w * wv4.w;
    Bs[lk + 0][lr] = bv4.x; Bs[lk + 1][lr] = bv4.y; Bs[lk + 2][lr] = bv4.z; Bs[lk + 3][lr] = bv4.w;
    __syncthreads();
#pragma unroll
    for (int kk = 0; kk < 8; kk++) {
      float av[8], bv[8];
      *(float4*)&av[0] = *(const float4*)&As[kk][ty * 8];
      *(float4*)&av[4] = *(const float4*)&As[kk][ty * 8 + 4];
      *(float4*)&bv[0] = *(const float4*)&Bs[kk][tx * 8];
      *(float4*)&bv[4] = *(const float4*)&Bs[kk][tx * 8 + 4];
#pragma unroll
      for (int a = 0; a < 8; a++)
#pragma unroll
        for (int b = 0; b < 8; b++) acc[a][b] += av[a] * bv[b];
    }
    __syncthreads();
  }
#pragma unroll
  for (int a = 0; a < 8; a++) {
    int gi = i0 + ty * 8 + a;
    float sqi = sq[gi];
    float outv[8];
#pragma unroll
    for (int b = 0; b < 8; b++) {
      int gj = j0 + tx * 8 + b;
      float v = sqi + sq[gj] - 2.f * acc[a][b];
      outv[b] = (gi == gj) ? 1.0f : v;
    }
    float* Cr = &C[(size_t)gi * Nn + j0 + tx * 8];
    *(float4*)&Cr[0] = *(float4*)&outv[0];
    *(float4*)&Cr[4] = *(float4*)&outv[4];
  }
}

// ---------------- degree counting ----------------
__global__ void k_count(const int* __restrict__ src, const int* __restrict__ dst,
                        int* __restrict__ degi, int* __restrict__ degrow) {
  int e = blockIdx.x * blockDim.x + threadIdx.x;
  if (e < Ee) {
    atomicAdd(&degi[dst[e]], 1);
    atomicAdd(&degrow[src[e]], 1);
  }
}

// ---------------- dis = (deg_in+1)^-0.5 ----------------
__global__ void k_dis(const int* __restrict__ degi, float* __restrict__ dis) {
  int i = blockIdx.x * 256 + threadIdx.x;
  dis[i] = rsqrtf((float)(degi[i] + 1));
}

// ---------------- histogram of (deg_in+1) + exclusive prefix -> binbase ----------------
__global__ void k_hist(const int* __restrict__ degi, int* __restrict__ binbase) {
  __shared__ int h[WCAP + 1];
  int t = threadIdx.x;
  if (t <= WCAP) h[t] = 0;
  __syncthreads();
  for (int i = t; i < Nn; i += 256) {
    int d = degi[i] + 1;
    if (d > WCAP) d = WCAP;
    atomicAdd(&h[d], 1);
  }
  __syncthreads();
  if (t == 0) {
    int run = 0;
    for (int b = 0; b <= WCAP; b++) { int c = h[b]; binbase[b] = run; run += c; }
  }
}

// ---------------- counting-sort scatter: perm (sorted pos -> row), rnk (row -> pos) ----------------
__global__ void k_scatter(const int* __restrict__ degi, const int* __restrict__ binbase,
                          int* __restrict__ bincnt, int* __restrict__ perm,
                          int* __restrict__ rnk) {
  int i = blockIdx.x * 256 + threadIdx.x;
  int d = degi[i] + 1;
  if (d > WCAP) d = WCAP;
  int pos = binbase[d] + atomicAdd(&bincnt[d], 1);
  perm[pos] = i;
  rnk[i] = pos;
}

// ---------------- per-chunk max degree (chunk = 64 consecutive sorted rows) ----------------
__global__ void k_wsub(const int* __restrict__ degi, const int* __restrict__ perm,
                       int* __restrict__ wsub) {
  int t = threadIdx.x;  // 64 threads, one per chunk
  int d = degi[perm[t * 64 + 63]] + 1;  // ascending sort -> max at end of chunk
  wsub[t] = d > WCAP ? WCAP : d;
}

// ---------------- per-(row, bank-group) histogram: group = src col & 7 ----------------
__global__ void k_cnt2(const int* __restrict__ src, const int* __restrict__ dst,
                       const int* __restrict__ rnk, int* __restrict__ gB) {
  int i = blockIdx.x * blockDim.x + threadIdx.x;
  int s, d;
  if (i < Ee) { s = src[i]; d = dst[i]; }
  else if (i < Ee + Nn) { s = d = i - Ee; }
  else return;
  int q = rnk[d];
  atomicAdd(&gB[q * 8 + (s & 7)], 1);
}

// in-place exclusive prefix over the 8 groups of each row
__global__ void k_gpre(int* __restrict__ gB) {
  int q = blockIdx.x * 256 + threadIdx.x;
  int run = 0;
#pragma unroll
  for (int g = 0; g < 8; g++) { int c = gB[q * 8 + g]; gB[q * 8 + g] = run; run += c; }
}

// ---------------- bucket-major ELL fill: ell0[p*Nn+q], p = group base + intra rank ----------------
__global__ void k_fill_ell(const int* __restrict__ src, const int* __restrict__ dst,
                           const float* __restrict__ dis, const int* __restrict__ rnk,
                           const int* __restrict__ gB, int* __restrict__ gslot,
                           int2* __restrict__ ell0) {
  int i = blockIdx.x * blockDim.x + threadIdx.x;
  int s, d;
  if (i < Ee) { s = src[i]; d = dst[i]; }
  else if (i < Ee + Nn) { s = d = i - Ee; }
  else return;
  int q = rnk[d];
  int g = s & 7;
  int p = gB[q * 8 + g] + atomicAdd(&gslot[q * 8 + g], 1);
  if (p < WCAP) ell0[(size_t)p * Nn + q] = make_int2(s, __float_as_int(dis[s] * dis[d]));
}

// ---------------- greedy slot scheduler: per chunk, balance bank-groups per slot ----------------
// One 64-thread block per chunk. Lane = row. Each slot: lanes claim a bank-group
// (largest-remaining-first) under per-half-wave caps via LDS ticket counters, so the
// 64 columns gathered at any slot are ~uniform mod 8 in both 32-lane halves.
__global__ __launch_bounds__(64) void k_sched(const int* __restrict__ degi,
                                              const int* __restrict__ perm,
                                              const int* __restrict__ gB,
                                              const int* __restrict__ gslot,
                                              const int* __restrict__ wsub,
                                              const int2* __restrict__ ell0,
                                              int2* __restrict__ ell) {
  __shared__ int cnt[16];  // [half][group]
  int lane = threadIdx.x;
  int q = blockIdx.x * 64 + lane;
  int half = lane >> 5;
  int deg = degi[perm[q]] + 1;
  if (deg > WCAP) deg = WCAP;
  int smax = wsub[blockIdx.x];

  int rem[8], ptr[8], base[8];
#pragma unroll
  for (int g = 0; g < 8; g++) {
    rem[g] = gslot[q * 8 + g];
    base[g] = gB[q * 8 + g];
    ptr[g] = 0;
  }

  for (int s = 0; s < smax; s++) {
    bool active = s < deg;
    unsigned long long am = __ballot(active);
    int act0 = __popcll(am & 0xFFFFFFFFull);
    int act1 = __popcll(am >> 32);
    int cap = (((half ? act1 : act0) + 7) >> 3) + 1;
    if (lane < 16) cnt[lane] = 0;
    __syncthreads();
    int chosen = -1, closed = 0;
    for (int round = 0; round < 8; round++) {
      if (__all(!(active && chosen < 0))) break;
      if (active && chosen < 0) {
        int best = -1, bestv = 0;
#pragma unroll
        for (int g = 0; g < 8; g++) {
          int rv = rem[g];
          bool ok = rv > 0 && !((closed >> g) & 1);
          if (ok && rv > bestv) { bestv = rv; best = g; }
        }
        if (best >= 0) {
          int t = atomicAdd(&cnt[half * 8 + best], 1);
          if (t < cap) chosen = best;
          else { atomicSub(&cnt[half * 8 + best], 1); closed |= 1 << best; }
        } else {
          closed = 0xFF;  // nothing available under caps; wait for fallback
        }
      }
      __syncthreads();
    }
    if (active && chosen < 0) {  // fallback: any non-empty bucket
      int best = -1, bestv = 0;
#pragma unroll
      for (int g = 0; g < 8; g++) {
        int rv = rem[g];
        if (rv > bestv) { bestv = rv; best = g; }
      }
      chosen = best;
    }
    if (active) {
      int p = base[chosen] + ptr[chosen];
      ptr[chosen]++; rem[chosen]--;
      ell[(size_t)s * Nn + q] = ell0[(size_t)p * Nn + q];
    }
    __syncthreads();
  }
}

// ---------------- fused 10-hop APPNP on a 4-column slab; h resident in LDS ----------------
// Chunk c = 64 sorted rows; (wave wv, chain rr) owns chunk rr*8+wv (interleaved so each
// wave gets one top-8 chunk -> per-wave slot totals balanced). Chain loops to its chunk's
// max degree ws[rr] (wave-uniform scalar branch). ELL slots are greedily bank-balanced
// (k_sched) so the random h4 gathers spread ~evenly over the 8 ds_read_b128 bank-groups.
template <int PASS>
__global__ __launch_bounds__(TPB, 4) void k_appnp(const float* __restrict__ xsrc,
                                                  float* __restrict__ dstp,
                                                  const int2* __restrict__ ell,
                                                  const int* __restrict__ perm,
                                                  const int* __restrict__ wsub,
                                                  const int* __restrict__ degrow) {
  extern __shared__ float4 h4[];  // Nn entries = 64 KB
  int j0 = blockIdx.x * CT;
  int tid = threadIdx.x;
  int wv = tid >> 6, ln = tid & 63;
  int qb = wv * 64 + ln;  // chunk rr*8+wv -> sorted position qb + rr*512

  // stage x0 slab into LDS, coalesced, original row order
#pragma unroll
  for (int rr = 0; rr < RPT; rr++) {
    int r = tid + rr * TPB;
    float4 v;
    v.x = xsrc[(size_t)(j0 + 0) * Nn + r];
    v.y = xsrc[(size_t)(j0 + 1) * Nn + r];
    v.z = xsrc[(size_t)(j0 + 2) * Nn + r];
    v.w = xsrc[(size_t)(j0 + 3) * Nn + r];
    h4[r] = v;
  }

  int ws[RPT];
#pragma unroll
  for (int rr = 0; rr < RPT; rr++)
    ws[rr] = __builtin_amdgcn_readfirstlane(wsub[rr * 8 + wv]);  // wave-uniform -> SGPR
  const int Wv = ws[RPT - 1];  // chunk index ascending in rr -> last is the wave max

  int rp[RPT];
#pragma unroll
  for (int rr = 0; rr < RPT; rr++) rp[rr] = perm[qb + rr * 512];

  __syncthreads();
  float4 x0r[RPT];
#pragma unroll
  for (int rr = 0; rr < RPT; rr++) x0r[rr] = h4[rp[rr]];

  float4 acc[RPT];
  for (int it = 0; it < HOPS; it++) {
    int2 cur[RPT];
#pragma unroll
    for (int rr = 0; rr < RPT; rr++) cur[rr] = ell[qb + rr * 512];  // slot 0 always exists
#pragma unroll
    for (int rr = 0; rr < RPT; rr++) acc[rr] = x0r[rr];  // alpha*x0 folded: res = 0.5*(x0+sum)
    for (int s = 0; s < Wv; s++) {
      int sn = s + 1;
      int2 nxt[RPT];
#pragma unroll
      for (int rr = 0; rr < RPT; rr++)
        if (sn < ws[rr]) nxt[rr] = ell[(size_t)sn * Nn + qb + rr * 512];
#pragma unroll
      for (int rr = 0; rr < RPT; rr++)
        if (s < ws[rr]) {
          float vv = __int_as_float(cur[rr].y);
          float4 hu = h4[cur[rr].x];
          acc[rr].x = fmaf(vv, hu.x, acc[rr].x);
          acc[rr].y = fmaf(vv, hu.y, acc[rr].y);
          acc[rr].z = fmaf(vv, hu.z, acc[rr].z);
          acc[rr].w = fmaf(vv, hu.w, acc[rr].w);
        }
#pragma unroll
      for (int rr = 0; rr < RPT; rr++)
        if (sn < ws[rr]) cur[rr] = nxt[rr];
    }
#pragma unroll
    for (int rr = 0; rr < RPT; rr++) {
      acc[rr].x *= 0.5f; acc[rr].y *= 0.5f; acc[rr].z *= 0.5f; acc[rr].w *= 0.5f;
    }
    __syncthreads();
#pragma unroll
    for (int rr = 0; rr < RPT; rr++) h4[rp[rr]] = acc[rr];  // scattered, bijective
    __syncthreads();
  }

  // writeback from h4, tid-linear (same global pattern as before)
  if (PASS == 1) {
#pragma unroll
    for (int rr = 0; rr < RPT; rr++) {
      int r = tid + rr * TPB;
      *(float4*)&dstp[(size_t)r * Nn + j0] = h4[r];
    }
  } else {
#pragma unroll
    for (int rr = 0; rr < RPT; rr++) {
      int r = tid + rr * TPB;
      float4 a = h4[r];
      float vals[4] = {a.x, a.y, a.z, a.w};
#pragma unroll
      for (int c = 0; c < 4; c++) {
        float v = vals[c];
        if (r == j0 + c) v *= 1.0f / ((float)degrow[r] + 1.0f);
        dstp[(size_t)(j0 + c) * Nn + r] = v;
      }
    }
  }
}

extern "C" void kernel_launch(void* const* d_in, const int* in_sizes, int n_in,
                              void* d_out, int out_size, void* d_ws, size_t ws_size,
                              hipStream_t stream) {
  const float* x = (const float*)d_in[0];  // [N,D]
  const float* w = (const float*)d_in[1];  // [D]
  const int* ei = (const int*)d_in[2];     // [2,E]
  const int* src = ei;
  const int* dstv = ei + Ee;
  float* out = (float*)d_out;

  // workspace layout (~72 MB)
  float* W1 = (float*)d_ws;                     // Nn*Nn : K
  float* sq = W1 + (size_t)Nn * Nn;             // Nn
  float* dis = sq + Nn;                         // Nn
  int2* ell = (int2*)(dis + Nn);                // WCAP*Nn (2 MB) final schedule
  int* degi = (int*)(ell + (size_t)WCAP * Nn);  // Nn  --- zeroed block start
  int* degrow = degi + Nn;                      // Nn
  int* bincnt = degrow + Nn;                    // WCAP+1
  int* gB = bincnt + (WCAP + 1);                // 8*Nn (group histogram -> prefix)
  int* gslot = gB + 8 * Nn;                     // 8*Nn --- zeroed block end
  int* binbase = gslot + 8 * Nn;                // WCAP+1
  int* perm = binbase + (WCAP + 1);             // Nn
  int* rnk = perm + Nn;                         // Nn
  int* wsub = rnk + Nn;                         // 64
  int2* ell0 = (int2*)(wsub + 64);              // WCAP*Nn (2 MB) bucket-major

  hipMemsetAsync(ell, 0, (size_t)WCAP * Nn * sizeof(int2), stream);
  hipMemsetAsync(degi, 0, sizeof(int) * (2 * Nn + (WCAP + 1) + 16 * Nn), stream);

  k_sq<<<Nn, 256, 0, stream>>>(x, w, sq);
  k_gemm<<<dim3(Nn / 128, Nn / 128), 256, 0, stream>>>(x, w, sq, W1);
  k_count<<<Ee / 256, 256, 0, stream>>>(src, dstv, degi, degrow);
  k_dis<<<Nn / 256, 256, 0, stream>>>(degi, dis);
  k_hist<<<1, 256, 0, stream>>>(degi, binbase);
  k_scatter<<<Nn / 256, 256, 0, stream>>>(degi, binbase, bincnt, perm, rnk);
  k_wsub<<<1, 64, 0, stream>>>(degi, perm, wsub);
  k_cnt2<<<(Ee + Nn + 255) / 256, 256, 0, stream>>>(src, dstv, rnk, gB);
  k_gpre<<<Nn / 256, 256, 0, stream>>>(gB);
  k_fill_ell<<<(Ee + Nn + 255) / 256, 256, 0, stream>>>(src, dstv, dis, rnk, gB, gslot, ell0);
  k_sched<<<64, 64, 0, stream>>>(degi, perm, gB, gslot, wsub, ell0, ell);

  // pass 1: kgg1 = APPNP(K) -> out (row-major)
  k_appnp<1><<<Nn / CT, TPB, Nn * sizeof(float4), stream>>>(W1, out, ell, perm, wsub, nullptr);
  // pass 2: in-place on out: reads kgg1 rows, writes final (kgg2^T, diag-scaled)
  k_appnp<2><<<Nn / CT, TPB, Nn * sizeof(float4), stream>>>(out, out, ell, perm, wsub, degrow);
}

// Round 4
// 1040.533 us; speedup vs baseline: 1.3765x; 1.3765x over previous
//
#include <hip/hip_runtime.h>
#include <stdint.h>

#define Nn 4096
#define Dd 512
#define Ee 65536
#define HOPS 10
#define TPB 512
#define RPT (Nn / TPB)  // 8 rows per thread
#define CT 4            // columns per block
#define WCAP 64         // ELL slot capacity (max in-degree+1; Poisson(16) max ~38)
#define BCOLS 1028      // [-2w*X (512) | X (512) | u | 1 | pad | pad]
#define KEXT 1536       // hi/lo-split extension K: [hi|hi|lo] x [hi|lo|hi]

typedef unsigned short ushortT;
typedef short bf16x8 __attribute__((ext_vector_type(8)));
typedef float f32x4 __attribute__((ext_vector_type(4)));

// ---------------- helpers ----------------
__device__ __forceinline__ unsigned short bf16r(float x) {  // RNE fp32->bf16
  unsigned int b = __float_as_uint(x);
  return (unsigned short)((b + 0x7FFFu + ((b >> 16) & 1u)) >> 16);
}
__device__ __forceinline__ float ubf(unsigned short h) {
  return __uint_as_float(((unsigned int)h) << 16);
}
__device__ __forceinline__ void gld16(const unsigned short* g, unsigned short* lds) {
  __builtin_amdgcn_global_load_lds(
      (const __attribute__((address_space(1))) unsigned int*)g,
      (__attribute__((address_space(3))) unsigned int*)lds, 16, 0, 0);
}

// ---------------- sq[i] = sum_d w_d * x[i,d]^2 ----------------
__global__ __launch_bounds__(256) void k_sq(const float* __restrict__ x,
                                            const float* __restrict__ w,
                                            float* __restrict__ sq) {
  int row = blockIdx.x;
  int tid = threadIdx.x;
  const float* xr = x + (size_t)row * Dd;
  float partial = 0.f;
  for (int d = tid; d < Dd; d += 256) {
    float xv = xr[d];
    partial += xv * xv * w[d];
  }
  for (int off = 32; off >= 1; off >>= 1) partial += __shfl_down(partial, off, 64);
  __shared__ float red[4];
  int wv = tid >> 6, ln = tid & 63;
  if (ln == 0) red[wv] = partial;
  __syncthreads();
  if (tid == 0) sq[row] = red[0] + red[1] + red[2] + red[3];
}

// ---------------- degree counting ----------------
__global__ void k_count(const int* __restrict__ src, const int* __restrict__ dst,
                        int* __restrict__ degi, int* __restrict__ degrow) {
  int e = blockIdx.x * blockDim.x + threadIdx.x;
  if (e < Ee) {
    atomicAdd(&degi[dst[e]], 1);
    atomicAdd(&degrow[src[e]], 1);
  }
}

// ---------------- dis = (deg_in+1)^-0.5 ; d2 = 1/(deg_row+1) ----------------
__global__ void k_dis(const int* __restrict__ degi, const int* __restrict__ degrow,
                      float* __restrict__ dis, float* __restrict__ d2) {
  int i = blockIdx.x * 256 + threadIdx.x;
  dis[i] = rsqrtf((float)(degi[i] + 1));
  d2[i] = 1.0f / ((float)degrow[i] + 1.0f);
}

// ---------------- histogram of (deg_in+1) + exclusive prefix -> binbase ----------------
__global__ void k_hist(const int* __restrict__ degi, int* __restrict__ binbase) {
  __shared__ int h[WCAP + 1];
  int t = threadIdx.x;
  if (t <= WCAP) h[t] = 0;
  __syncthreads();
  for (int i = t; i < Nn; i += 256) {
    int d = degi[i] + 1;
    if (d > WCAP) d = WCAP;
    atomicAdd(&h[d], 1);
  }
  __syncthreads();
  if (t == 0) {
    int run = 0;
    for (int b = 0; b <= WCAP; b++) { int c = h[b]; binbase[b] = run; run += c; }
  }
}

// ---------------- counting-sort scatter: perm (sorted pos -> row), rnk (row -> pos) ----------------
__global__ void k_scatter(const int* __restrict__ degi, const int* __restrict__ binbase,
                          int* __restrict__ bincnt, int* __restrict__ perm,
                          int* __restrict__ rnk) {
  int i = blockIdx.x * 256 + threadIdx.x;
  int d = degi[i] + 1;
  if (d > WCAP) d = WCAP;
  int pos = binbase[d] + atomicAdd(&bincnt[d], 1);
  perm[pos] = i;
  rnk[i] = pos;
}

// ---------------- per-(wave,chain) slot bounds ----------------
__global__ void k_wsub(const int* __restrict__ degi, const int* __restrict__ perm,
                       int* __restrict__ wsub) {
  int t = threadIdx.x;
  int d = degi[perm[t * 64 + 63]] + 1;
  wsub[t] = d > WCAP ? WCAP : d;
}

// ---------------- ELL fill (slot-major, sorted-position indexed) ----------------
__global__ void k_fill_ell(const int* __restrict__ src, const int* __restrict__ dst,
                           const float* __restrict__ dis, const int* __restrict__ rnk,
                           int* __restrict__ slot, int2* __restrict__ ell) {
  int i = blockIdx.x * blockDim.x + threadIdx.x;
  if (i < Ee) {
    int s = src[i], d = dst[i];
    int p = atomicAdd(&slot[d], 1);
    if (p < WCAP) ell[(size_t)p * Nn + rnk[d]] = make_int2(s, __float_as_int(dis[s] * dis[d]));
  } else if (i < Ee + Nn) {
    int v = i - Ee;
    int p = atomicAdd(&slot[v], 1);
    if (p < WCAP) ell[(size_t)p * Nn + rnk[v]] = make_int2(v, __float_as_int(dis[v] * dis[v]));
  }
}

// ---------------- XcatT[c][r]: c<512: -2*w_c*X[r][c]; c<1024: X[r][c-512] ----------------
__global__ __launch_bounds__(256) void k_xpose(const float* __restrict__ x,
                                               const float* __restrict__ w,
                                               float* __restrict__ xcat) {
  __shared__ float tile[32][33];
  int cx = blockIdx.x, rx = blockIdx.y;
  int t = threadIdx.x, txc = t & 31, tyc = t >> 5;
#pragma unroll
  for (int i = 0; i < 4; i++) {
    int a = tyc + i * 8;
    tile[a][txc] = x[(size_t)(rx * 32 + a) * Dd + cx * 32 + txc];
  }
  __syncthreads();
#pragma unroll
  for (int i = 0; i < 4; i++) {
    int a = tyc + i * 8;
    int c = cx * 32 + a;
    float v = tile[txc][a];
    xcat[(size_t)c * Nn + rx * 32 + txc] = -2.0f * w[c] * v;
    xcat[(size_t)(512 + c) * Nn + rx * 32 + txc] = v;
  }
}

// ---------------- XcatT tail rows: u (=sq), ones, pad ----------------
__global__ void k_tail(const float* __restrict__ sq, float* __restrict__ xcat) {
  int r = blockIdx.x * 256 + threadIdx.x;
  xcat[(size_t)1024 * Nn + r] = sq[r];
  xcat[(size_t)1025 * Nn + r] = 1.0f;
  xcat[(size_t)1026 * Nn + r] = 0.0f;
  xcat[(size_t)1027 * Nn + r] = 0.0f;
}

// ---------------- fused 10-hop APPNP on a 4-column slab; h resident in LDS ----------------
// MODE 0: B-pass. xsrc = XcatT (1028 virtual columns); writes Aext/Bext bf16 hi/lo split
//         (A-ext = [B1hi|B1hi|B1lo], B-ext = [B2hi|B2lo|B2hi]) and mu/m1 vectors.
// MODE 1: M-pass. Input = identity (synthesized); writes Mb = bf16(M) row-major.
// Inner structure = round-1 proven version (494 us/1024-block pass).
template <int MODE>
__global__ __launch_bounds__(TPB, 4) void k_appnp(const float* __restrict__ xsrc,
                                                  unsigned short* __restrict__ mb,
                                                  unsigned short* __restrict__ aext,
                                                  unsigned short* __restrict__ bext,
                                                  float* __restrict__ mu,
                                                  float* __restrict__ m1,
                                                  const int2* __restrict__ ell,
                                                  const int* __restrict__ perm,
                                                  const int* __restrict__ wsub) {
  extern __shared__ float4 h4[];  // Nn entries = 64 KB
  int j0 = blockIdx.x * CT;
  int tid = threadIdx.x;
  int wv = tid >> 6, ln = tid & 63;
  int qb = wv * 512 + ln;

#pragma unroll
  for (int rr = 0; rr < RPT; rr++) {
    int r = tid + rr * TPB;
    float4 v;
    if (MODE == 1) {
      v.x = (r == j0 + 0) ? 1.f : 0.f;
      v.y = (r == j0 + 1) ? 1.f : 0.f;
      v.z = (r == j0 + 2) ? 1.f : 0.f;
      v.w = (r == j0 + 3) ? 1.f : 0.f;
    } else {
      v.x = xsrc[(size_t)(j0 + 0) * Nn + r];
      v.y = xsrc[(size_t)(j0 + 1) * Nn + r];
      v.z = xsrc[(size_t)(j0 + 2) * Nn + r];
      v.w = xsrc[(size_t)(j0 + 3) * Nn + r];
    }
    h4[r] = v;
  }

  int ws[RPT];
#pragma unroll
  for (int rr = 0; rr < RPT; rr++)
    ws[rr] = __builtin_amdgcn_readfirstlane(wsub[wv * 8 + rr]);
  const int Wv = ws[RPT - 1];

  int rp[RPT];
#pragma unroll
  for (int rr = 0; rr < RPT; rr++) rp[rr] = perm[qb + rr * 64];

  __syncthreads();
  float4 x0r[RPT];
#pragma unroll
  for (int rr = 0; rr < RPT; rr++) x0r[rr] = h4[rp[rr]];

  float4 acc[RPT];
  for (int it = 0; it < HOPS; it++) {
    int2 cur[RPT];
#pragma unroll
    for (int rr = 0; rr < RPT; rr++) cur[rr] = ell[qb + rr * 64];
#pragma unroll
    for (int rr = 0; rr < RPT; rr++) acc[rr] = x0r[rr];
    for (int s = 0; s < Wv; s++) {
      int sn = s + 1;
      int2 nxt[RPT];
#pragma unroll
      for (int rr = 0; rr < RPT; rr++)
        if (sn < ws[rr]) nxt[rr] = ell[(size_t)sn * Nn + qb + rr * 64];
#pragma unroll
      for (int rr = 0; rr < RPT; rr++)
        if (s < ws[rr]) {
          float vv = __int_as_float(cur[rr].y);
          float4 hu = h4[cur[rr].x];
          acc[rr].x = fmaf(vv, hu.x, acc[rr].x);
          acc[rr].y = fmaf(vv, hu.y, acc[rr].y);
          acc[rr].z = fmaf(vv, hu.z, acc[rr].z);
          acc[rr].w = fmaf(vv, hu.w, acc[rr].w);
        }
#pragma unroll
      for (int rr = 0; rr < RPT; rr++)
        if (sn < ws[rr]) cur[rr] = nxt[rr];
    }
#pragma unroll
    for (int rr = 0; rr < RPT; rr++) {
      acc[rr].x *= 0.5f; acc[rr].y *= 0.5f; acc[rr].z *= 0.5f; acc[rr].w *= 0.5f;
    }
    __syncthreads();
#pragma unroll
    for (int rr = 0; rr < RPT; rr++) h4[rp[rr]] = acc[rr];
    __syncthreads();
  }

  if (MODE == 1) {
#pragma unroll
    for (int rr = 0; rr < RPT; rr++) {
      int r = tid + rr * TPB;
      float4 a = h4[r];
      ushort4 o = make_ushort4(bf16r(a.x), bf16r(a.y), bf16r(a.z), bf16r(a.w));
      *(ushort4*)&mb[(size_t)r * Nn + j0] = o;
    }
  } else {
    if (j0 < 1024) {
#pragma unroll
      for (int rr = 0; rr < RPT; rr++) {
        int r = tid + rr * TPB;
        float4 a = h4[r];
        ushort4 hi = make_ushort4(bf16r(a.x), bf16r(a.y), bf16r(a.z), bf16r(a.w));
        ushort4 lo = make_ushort4(bf16r(a.x - ubf(hi.x)), bf16r(a.y - ubf(hi.y)),
                                  bf16r(a.z - ubf(hi.z)), bf16r(a.w - ubf(hi.w)));
        if (j0 < 512) {  // B1 = M(-2w.X): A-ext = [hi | hi | lo]
          *(ushort4*)&aext[(size_t)r * KEXT + j0] = hi;
          *(ushort4*)&aext[(size_t)r * KEXT + 512 + j0] = hi;
          *(ushort4*)&aext[(size_t)r * KEXT + 1024 + j0] = lo;
        } else {  // B2 = M X: B-ext = [hi | lo | hi]
          int c = j0 - 512;
          *(ushort4*)&bext[(size_t)r * KEXT + c] = hi;
          *(ushort4*)&bext[(size_t)r * KEXT + 512 + c] = lo;
          *(ushort4*)&bext[(size_t)r * KEXT + 1024 + c] = hi;
        }
      }
    } else if (j0 == 1024) {
#pragma unroll
      for (int rr = 0; rr < RPT; rr++) {
        int r = tid + rr * TPB;
        float4 a = h4[r];
        mu[r] = a.x;  // M u
        m1[r] = a.y;  // M 1
      }
    }
  }
}

// ---------------- bf16 MFMA GEMM: out = Mb*Mb^T + Aext*Bext^T + rank2, diag*d2 ----------------
// 128x128 tile, BK=32, 4 waves (2x2 of 64x64), mfma_f32_16x16x32_bf16.
// LDS tiles [128][32] ushort with chunk XOR-swizzle (c ^= (row>>1)&3) applied on the
// pre-swizzled GLOBAL source (global_load_lds dest must be linear) -> 2-way-only bank use.
__device__ __forceinline__ void mm_step(const unsigned short* __restrict__ Ap, int lda,
                                        const unsigned short* __restrict__ Bp, int ldb,
                                        unsigned short* As, unsigned short* Bs,
                                        int i0, int j0, int k0, int l, int w, int wr,
                                        int wc, f32x4 acc[4][4]) {
#pragma unroll
  for (int j = 0; j < 2; j++) {
    int row = (w * 2 + j) * 16 + (l >> 2);
    int clog = (l & 3) ^ ((row >> 1) & 3);
    gld16(Ap + (size_t)(i0 + row) * lda + k0 + clog * 8, As + (w * 2 + j) * 512);
    gld16(Bp + (size_t)(j0 + row) * ldb + k0 + clog * 8, Bs + (w * 2 + j) * 512);
  }
  __syncthreads();
  bf16x8 af[4], bg[4];
#pragma unroll
  for (int m = 0; m < 4; m++) {
    int ar = wr * 64 + m * 16 + (l & 15);
    af[m] = *(const bf16x8*)(As + ar * 32 + (((l >> 4) ^ ((ar >> 1) & 3))) * 8);
    int br = wc * 64 + m * 16 + (l & 15);
    bg[m] = *(const bf16x8*)(Bs + br * 32 + (((l >> 4) ^ ((br >> 1) & 3))) * 8);
  }
#pragma unroll
  for (int m = 0; m < 4; m++)
#pragma unroll
    for (int n = 0; n < 4; n++)
      acc[m][n] = __builtin_amdgcn_mfma_f32_16x16x32_bf16(af[m], bg[n], acc[m][n], 0, 0, 0);
  __syncthreads();
}

__global__ __launch_bounds__(256) void k_mm(const unsigned short* __restrict__ Mb,
                                            const unsigned short* __restrict__ Aext,
                                            const unsigned short* __restrict__ Bext,
                                            const float* __restrict__ mu,
                                            const float* __restrict__ m1,
                                            const float* __restrict__ d2,
                                            float* __restrict__ out) {
  __shared__ unsigned short As[128 * 32];
  __shared__ unsigned short Bs[128 * 32];
  int i0 = blockIdx.y * 128, j0 = blockIdx.x * 128;
  int tid = threadIdx.x, l = tid & 63, w = tid >> 6;
  int wr = w >> 1, wc = w & 1;
  f32x4 acc[4][4];
#pragma unroll
  for (int m = 0; m < 4; m++)
#pragma unroll
    for (int n = 0; n < 4; n++) acc[m][n] = (f32x4){0.f, 0.f, 0.f, 0.f};

  for (int k0 = 0; k0 < Nn; k0 += 32)
    mm_step(Mb, Nn, Mb, Nn, As, Bs, i0, j0, k0, l, w, wr, wc, acc);
  for (int k0 = 0; k0 < KEXT; k0 += 32)
    mm_step(Aext, KEXT, Bext, KEXT, As, Bs, i0, j0, k0, l, w, wr, wc, acc);

#pragma unroll
  for (int m = 0; m < 4; m++) {
#pragma unroll
    for (int n = 0; n < 4; n++) {
#pragma unroll
      for (int q = 0; q < 4; q++) {
        int gi = i0 + wr * 64 + m * 16 + ((l >> 4) << 2) + q;
        int gj = j0 + wc * 64 + n * 16 + (l & 15);
        float v = acc[m][n][q] + mu[gi] * m1[gj] + m1[gi] * mu[gj];
        if (gi == gj) v *= d2[gi];
        out[(size_t)gi * Nn + gj] = v;
      }
    }
  }
}

extern "C" void kernel_launch(void* const* d_in, const int* in_sizes, int n_in,
                              void* d_out, int out_size, void* d_ws, size_t ws_size,
                              hipStream_t stream) {
  const float* x = (const float*)d_in[0];  // [N,D]
  const float* w = (const float*)d_in[1];  // [D]
  const int* ei = (const int*)d_in[2];     // [2,E]
  const int* src = ei;
  const int* dstv = ei + Ee;
  float* out = (float*)d_out;

  // workspace (~61 MB). XcatT (16.8MB) aliases Mb (33.5MB): XcatT dies before M-pass writes Mb.
  unsigned short* Mb = (unsigned short*)d_ws;                       // [4096][4096] bf16
  float* xcat = (float*)d_ws;                                       // [1028][4096] f32 (alias)
  unsigned short* aext = (unsigned short*)((char*)d_ws + (size_t)Nn * Nn * 2);  // [4096][1536]
  unsigned short* bext = aext + (size_t)Nn * KEXT;                  // [4096][1536]
  int2* ell = (int2*)(bext + (size_t)Nn * KEXT);                    // WCAP*Nn (2 MB)
  float* sq = (float*)(ell + (size_t)WCAP * Nn);                    // Nn
  float* dis = sq + Nn;                                             // Nn
  float* d2 = dis + Nn;                                             // Nn
  float* mu = d2 + Nn;                                              // Nn
  float* m1 = mu + Nn;                                              // Nn
  int* degi = (int*)(m1 + Nn);                                      // Nn -- zero block start
  int* degrow = degi + Nn;                                          // Nn
  int* slotcnt = degrow + Nn;                                       // Nn
  int* bincnt = slotcnt + Nn;                                       // WCAP+1 -- zero block end
  int* binbase = bincnt + (WCAP + 1);                               // WCAP+1
  int* perm = binbase + (WCAP + 1);                                 // Nn
  int* rnk = perm + Nn;                                             // Nn
  int* wsub = rnk + Nn;                                             // 64

  hipMemsetAsync(ell, 0, (size_t)WCAP * Nn * sizeof(int2), stream);
  hipMemsetAsync(degi, 0, sizeof(int) * (3 * Nn + (WCAP + 1)), stream);

  k_sq<<<Nn, 256, 0, stream>>>(x, w, sq);
  k_count<<<Ee / 256, 256, 0, stream>>>(src, dstv, degi, degrow);
  k_dis<<<Nn / 256, 256, 0, stream>>>(degi, degrow, dis, d2);
  k_hist<<<1, 256, 0, stream>>>(degi, binbase);
  k_scatter<<<Nn / 256, 256, 0, stream>>>(degi, binbase, bincnt, perm, rnk);
  k_wsub<<<1, 64, 0, stream>>>(degi, perm, wsub);
  k_fill_ell<<<(Ee + Nn + 255) / 256, 256, 0, stream>>>(src, dstv, dis, rnk, slotcnt, ell);
  k_xpose<<<dim3(16, 128), 256, 0, stream>>>(x, w, xcat);
  k_tail<<<Nn / 256, 256, 0, stream>>>(sq, xcat);

  // B-pass: [B1|B2|mu|m1] = APPNP(XcatT rows) -> ext arrays (bf16 hi/lo) + vectors
  k_appnp<0><<<BCOLS / CT, TPB, Nn * sizeof(float4), stream>>>(xcat, nullptr, aext, bext, mu,
                                                               m1, ell, perm, wsub);
  // M-pass: Mb = bf16(APPNP(I))
  k_appnp<1><<<Nn / CT, TPB, Nn * sizeof(float4), stream>>>(nullptr, Mb, nullptr, nullptr,
                                                            nullptr, nullptr, ell, perm, wsub);
  // out = Mb Mb^T + Aext Bext^T + mu m1^T + m1 mu^T ; diag *= d2
  k_mm<<<dim3(Nn / 128, Nn / 128), 256, 0, stream>>>(Mb, aext, bext, mu, m1, d2, out);
}

// Round 6
// 971.721 us; speedup vs baseline: 1.4740x; 1.0708x over previous
//
#include <hip/hip_runtime.h>
#include <stdint.h>

#define Nn 4096
#define Dd 512
#define Ee 65536
#define HOPS 10
#define TPB 512
#define RPT (Nn / TPB)  // 8 rows per thread
#define CT 4            // columns per block
#define WCAP 64         // ELL slot capacity (max in-degree+1; Poisson(16) max ~38)
#define BCOLS 516       // [X (512) | u | 1 | pad | pad]  (B1 = (MX)diag(-2w): no extra sweep)
#define KEXT 1536       // hi/lo-split extension K: [Phi|Phi|Plo] x [Yhi|Ylo|Yhi]

typedef short bf16x8 __attribute__((ext_vector_type(8)));
typedef float f32x4 __attribute__((ext_vector_type(4)));

// ---------------- helpers ----------------
__device__ __forceinline__ unsigned short bf16r(float x) {  // RNE fp32->bf16
  unsigned int b = __float_as_uint(x);
  return (unsigned short)((b + 0x7FFFu + ((b >> 16) & 1u)) >> 16);
}
__device__ __forceinline__ float ubf(unsigned short h) {
  return __uint_as_float(((unsigned int)h) << 16);
}
__device__ __forceinline__ void gld16(const unsigned short* g, unsigned short* lds) {
  __builtin_amdgcn_global_load_lds(
      (const __attribute__((address_space(1))) unsigned int*)g,
      (__attribute__((address_space(3))) unsigned int*)lds, 16, 0, 0);
}

// ---------------- sq[i] = sum_d w_d * x[i,d]^2 ----------------
__global__ __launch_bounds__(256) void k_sq(const float* __restrict__ x,
                                            const float* __restrict__ w,
                                            float* __restrict__ sq) {
  int row = blockIdx.x;
  int tid = threadIdx.x;
  const float* xr = x + (size_t)row * Dd;
  float partial = 0.f;
  for (int d = tid; d < Dd; d += 256) {
    float xv = xr[d];
    partial += xv * xv * w[d];
  }
  for (int off = 32; off >= 1; off >>= 1) partial += __shfl_down(partial, off, 64);
  __shared__ float red[4];
  int wv = tid >> 6, ln = tid & 63;
  if (ln == 0) red[wv] = partial;
  __syncthreads();
  if (tid == 0) sq[row] = red[0] + red[1] + red[2] + red[3];
}

// ---------------- degree counting ----------------
__global__ void k_count(const int* __restrict__ src, const int* __restrict__ dst,
                        int* __restrict__ degi, int* __restrict__ degrow) {
  int e = blockIdx.x * blockDim.x + threadIdx.x;
  if (e < Ee) {
    atomicAdd(&degi[dst[e]], 1);
    atomicAdd(&degrow[src[e]], 1);
  }
}

// ---------------- dis = (deg_in+1)^-0.5 ; d2 = 1/(deg_row+1) ----------------
__global__ void k_dis(const int* __restrict__ degi, const int* __restrict__ degrow,
                      float* __restrict__ dis, float* __restrict__ d2) {
  int i = blockIdx.x * 256 + threadIdx.x;
  dis[i] = rsqrtf((float)(degi[i] + 1));
  d2[i] = 1.0f / ((float)degrow[i] + 1.0f);
}

// ---------------- histogram of (deg_in+1) + exclusive prefix -> binbase ----------------
__global__ void k_hist(const int* __restrict__ degi, int* __restrict__ binbase) {
  __shared__ int h[WCAP + 1];
  int t = threadIdx.x;
  if (t <= WCAP) h[t] = 0;
  __syncthreads();
  for (int i = t; i < Nn; i += 256) {
    int d = degi[i] + 1;
    if (d > WCAP) d = WCAP;
    atomicAdd(&h[d], 1);
  }
  __syncthreads();
  if (t == 0) {
    int run = 0;
    for (int b = 0; b <= WCAP; b++) { int c = h[b]; binbase[b] = run; run += c; }
  }
}

// ---------------- counting-sort scatter: perm (sorted pos -> row), rnk (row -> pos) ----------------
__global__ void k_scatter(const int* __restrict__ degi, const int* __restrict__ binbase,
                          int* __restrict__ bincnt, int* __restrict__ perm,
                          int* __restrict__ rnk) {
  int i = blockIdx.x * 256 + threadIdx.x;
  int d = degi[i] + 1;
  if (d > WCAP) d = WCAP;
  int pos = binbase[d] + atomicAdd(&bincnt[d], 1);
  perm[pos] = i;
  rnk[i] = pos;
}

// ---------------- per-(wave,chain) slot bounds ----------------
__global__ void k_wsub(const int* __restrict__ degi, const int* __restrict__ perm,
                       int* __restrict__ wsub) {
  int t = threadIdx.x;
  int d = degi[perm[t * 64 + 63]] + 1;
  wsub[t] = d > WCAP ? WCAP : d;
}

// ---------------- ELL fill (slot-major, sorted-position indexed) ----------------
__global__ void k_fill_ell(const int* __restrict__ src, const int* __restrict__ dst,
                           const float* __restrict__ dis, const int* __restrict__ rnk,
                           int* __restrict__ slot, int2* __restrict__ ell) {
  int i = blockIdx.x * blockDim.x + threadIdx.x;
  if (i < Ee) {
    int s = src[i], d = dst[i];
    int p = atomicAdd(&slot[d], 1);
    if (p < WCAP) ell[(size_t)p * Nn + rnk[d]] = make_int2(s, __float_as_int(dis[s] * dis[d]));
  } else if (i < Ee + Nn) {
    int v = i - Ee;
    int p = atomicAdd(&slot[v], 1);
    if (p < WCAP) ell[(size_t)p * Nn + rnk[v]] = make_int2(v, __float_as_int(dis[v] * dis[v]));
  }
}

// ---------------- XcatT[c][r] = X[r][c] (transposed X only) ----------------
__global__ __launch_bounds__(256) void k_xpose(const float* __restrict__ x,
                                               float* __restrict__ xcat) {
  __shared__ float tile[32][33];
  int cx = blockIdx.x, rx = blockIdx.y;
  int t = threadIdx.x, txc = t & 31, tyc = t >> 5;
#pragma unroll
  for (int i = 0; i < 4; i++) {
    int a = tyc + i * 8;
    tile[a][txc] = x[(size_t)(rx * 32 + a) * Dd + cx * 32 + txc];
  }
  __syncthreads();
#pragma unroll
  for (int i = 0; i < 4; i++) {
    int a = tyc + i * 8;
    int c = cx * 32 + a;
    xcat[(size_t)c * Nn + rx * 32 + txc] = tile[txc][a];
  }
}

// ---------------- XcatT tail rows: u (=sq), ones, pad ----------------
__global__ void k_tail(const float* __restrict__ sq, float* __restrict__ xcat) {
  int r = blockIdx.x * 256 + threadIdx.x;
  xcat[(size_t)512 * Nn + r] = sq[r];
  xcat[(size_t)513 * Nn + r] = 1.0f;
  xcat[(size_t)514 * Nn + r] = 0.0f;
  xcat[(size_t)515 * Nn + r] = 0.0f;
}

// ---------------- fused 10-hop APPNP on a 4-column slab; h resident in LDS ----------------
// MODE 0: B-pass. xsrc = XcatT [X|u|1]; per col slab Y=MX: writes BOTH ext operands
//         (aext = [Phi|Phi|Plo] with P = -2w*Y; bext = [Yhi|Ylo|Yhi]) and mu/m1.
// MODE 1: M-pass. Input = identity (synthesized); writes Mb = bf16(M) row-major.
template <int MODE>
__global__ __launch_bounds__(TPB, 4) void k_appnp(const float* __restrict__ xsrc,
                                                  const float* __restrict__ wp,
                                                  unsigned short* __restrict__ mb,
                                                  unsigned short* __restrict__ aext,
                                                  unsigned short* __restrict__ bext,
                                                  float* __restrict__ mu,
                                                  float* __restrict__ m1,
                                                  const int2* __restrict__ ell,
                                                  const int* __restrict__ perm,
                                                  const int* __restrict__ wsub) {
  extern __shared__ float4 h4[];  // Nn entries = 64 KB
  int j0 = blockIdx.x * CT;
  int tid = threadIdx.x;
  int wv = tid >> 6, ln = tid & 63;
  int qb = wv * 512 + ln;

#pragma unroll
  for (int rr = 0; rr < RPT; rr++) {
    int r = tid + rr * TPB;
    float4 v;
    if (MODE == 1) {
      v.x = (r == j0 + 0) ? 1.f : 0.f;
      v.y = (r == j0 + 1) ? 1.f : 0.f;
      v.z = (r == j0 + 2) ? 1.f : 0.f;
      v.w = (r == j0 + 3) ? 1.f : 0.f;
    } else {
      v.x = xsrc[(size_t)(j0 + 0) * Nn + r];
      v.y = xsrc[(size_t)(j0 + 1) * Nn + r];
      v.z = xsrc[(size_t)(j0 + 2) * Nn + r];
      v.w = xsrc[(size_t)(j0 + 3) * Nn + r];
    }
    h4[r] = v;
  }

  int ws[RPT];
#pragma unroll
  for (int rr = 0; rr < RPT; rr++)
    ws[rr] = __builtin_amdgcn_readfirstlane(wsub[wv * 8 + rr]);
  const int Wv = ws[RPT - 1];

  int rp[RPT];
#pragma unroll
  for (int rr = 0; rr < RPT; rr++) rp[rr] = perm[qb + rr * 64];

  __syncthreads();
  float4 x0r[RPT];
#pragma unroll
  for (int rr = 0; rr < RPT; rr++) x0r[rr] = h4[rp[rr]];

  float4 acc[RPT];
  for (int it = 0; it < HOPS; it++) {
    int2 cur[RPT];
#pragma unroll
    for (int rr = 0; rr < RPT; rr++) cur[rr] = ell[qb + rr * 64];
#pragma unroll
    for (int rr = 0; rr < RPT; rr++) acc[rr] = x0r[rr];
    for (int s = 0; s < Wv; s++) {
      int sn = s + 1;
      int2 nxt[RPT];
#pragma unroll
      for (int rr = 0; rr < RPT; rr++)
        if (sn < ws[rr]) nxt[rr] = ell[(size_t)sn * Nn + qb + rr * 64];
#pragma unroll
      for (int rr = 0; rr < RPT; rr++)
        if (s < ws[rr]) {
          float vv = __int_as_float(cur[rr].y);
          float4 hu = h4[cur[rr].x];
          acc[rr].x = fmaf(vv, hu.x, acc[rr].x);
          acc[rr].y = fmaf(vv, hu.y, acc[rr].y);
          acc[rr].z = fmaf(vv, hu.z, acc[rr].z);
          acc[rr].w = fmaf(vv, hu.w, acc[rr].w);
        }
#pragma unroll
      for (int rr = 0; rr < RPT; rr++)
        if (sn < ws[rr]) cur[rr] = nxt[rr];
    }
#pragma unroll
    for (int rr = 0; rr < RPT; rr++) {
      acc[rr].x *= 0.5f; acc[rr].y *= 0.5f; acc[rr].z *= 0.5f; acc[rr].w *= 0.5f;
    }
    __syncthreads();
#pragma unroll
    for (int rr = 0; rr < RPT; rr++) h4[rp[rr]] = acc[rr];
    __syncthreads();
  }

  if (MODE == 1) {
#pragma unroll
    for (int rr = 0; rr < RPT; rr++) {
      int r = tid + rr * TPB;
      float4 a = h4[r];
      ushort4 o = make_ushort4(bf16r(a.x), bf16r(a.y), bf16r(a.z), bf16r(a.w));
      *(ushort4*)&mb[(size_t)r * Nn + j0] = o;
    }
  } else {
    if (j0 < 512) {
      float w0 = -2.f * wp[j0 + 0], w1 = -2.f * wp[j0 + 1];
      float w2 = -2.f * wp[j0 + 2], w3 = -2.f * wp[j0 + 3];
#pragma unroll
      for (int rr = 0; rr < RPT; rr++) {
        int r = tid + rr * TPB;
        float4 a = h4[r];
        ushort4 yhi = make_ushort4(bf16r(a.x), bf16r(a.y), bf16r(a.z), bf16r(a.w));
        ushort4 ylo = make_ushort4(bf16r(a.x - ubf(yhi.x)), bf16r(a.y - ubf(yhi.y)),
                                   bf16r(a.z - ubf(yhi.z)), bf16r(a.w - ubf(yhi.w)));
        float4 p = make_float4(w0 * a.x, w1 * a.y, w2 * a.z, w3 * a.w);
        ushort4 phi = make_ushort4(bf16r(p.x), bf16r(p.y), bf16r(p.z), bf16r(p.w));
        ushort4 plo = make_ushort4(bf16r(p.x - ubf(phi.x)), bf16r(p.y - ubf(phi.y)),
                                   bf16r(p.z - ubf(phi.z)), bf16r(p.w - ubf(phi.w)));
        *(ushort4*)&bext[(size_t)r * KEXT + j0] = yhi;
        *(ushort4*)&bext[(size_t)r * KEXT + 512 + j0] = ylo;
        *(ushort4*)&bext[(size_t)r * KEXT + 1024 + j0] = yhi;
        *(ushort4*)&aext[(size_t)r * KEXT + j0] = phi;
        *(ushort4*)&aext[(size_t)r * KEXT + 512 + j0] = phi;
        *(ushort4*)&aext[(size_t)r * KEXT + 1024 + j0] = plo;
      }
    } else if (j0 == 512) {
#pragma unroll
      for (int rr = 0; rr < RPT; rr++) {
        int r = tid + rr * TPB;
        float4 a = h4[r];
        mu[r] = a.x;  // M u
        m1[r] = a.y;  // M 1
      }
    }
  }
}

// ---------------- bf16 MFMA GEMM: out = Mb*Mb^T + Aext*Bext^T + rank2, diag*d2 ----------------
// 128x128 tile, BK=64 (fewer barrier drains than BK=32), 4 waves (2x2 of 64x64).
// LDS [128][64] ushort = 128B rows; chunk XOR-swizzle slot = c ^ (row&7) gives uniform
// bank-group coverage on ds_read_b128 (dest of global_load_lds stays linear; source
// address carries the swizzle). Bijective XCD swizzle on the 1024-block grid for L2 reuse.
__device__ __forceinline__ void mm_step(const unsigned short* __restrict__ Ap, int lda,
                                        const unsigned short* __restrict__ Bp, int ldb,
                                        unsigned short* As, unsigned short* Bs,
                                        int i0, int j0, int k0, int l, int w, int wr,
                                        int wc, f32x4 acc[4][4]) {
  int rsub = w * 8 + (l >> 3);              // row within 32-row round
  int scg = ((l & 7) ^ (l >> 3)) * 8;       // pre-swizzled source chunk offset (ushorts)
#pragma unroll
  for (int r = 0; r < 4; r++) {
    int row = r * 32 + rsub;
    gld16(Ap + (size_t)(i0 + row) * lda + k0 + scg, As + (r * 32 + w * 8) * 64);
    gld16(Bp + (size_t)(j0 + row) * ldb + k0 + scg, Bs + (r * 32 + w * 8) * 64);
  }
  __syncthreads();
#pragma unroll
  for (int q = 0; q < 2; q++) {
    bf16x8 af[4], bg[4];
#pragma unroll
    for (int m = 0; m < 4; m++) {
      int ar = wr * 64 + m * 16 + (l & 15);
      af[m] = *(const bf16x8*)(As + ar * 64 + ((((l >> 4) + 4 * q) ^ (ar & 7)) * 8));
      int br = wc * 64 + m * 16 + (l & 15);
      bg[m] = *(const bf16x8*)(Bs + br * 64 + ((((l >> 4) + 4 * q) ^ (br & 7)) * 8));
    }
#pragma unroll
    for (int m = 0; m < 4; m++)
#pragma unroll
      for (int n = 0; n < 4; n++)
        acc[m][n] = __builtin_amdgcn_mfma_f32_16x16x32_bf16(af[m], bg[n], acc[m][n], 0, 0, 0);
  }
  __syncthreads();
}

__global__ __launch_bounds__(256) void k_mm(const unsigned short* __restrict__ Mb,
                                            const unsigned short* __restrict__ Aext,
                                            const unsigned short* __restrict__ Bext,
                                            const float* __restrict__ mu,
                                            const float* __restrict__ m1,
                                            const float* __restrict__ d2,
                                            float* __restrict__ out) {
  __shared__ unsigned short As[128 * 64];
  __shared__ unsigned short Bs[128 * 64];
  int lid = blockIdx.y * 32 + blockIdx.x;
  int swz = (lid & 7) * 128 + (lid >> 3);  // 1024 % 8 == 0 -> bijective
  int i0 = (swz >> 5) * 128, j0 = (swz & 31) * 128;
  int tid = threadIdx.x, l = tid & 63, w = tid >> 6;
  int wr = w >> 1, wc = w & 1;
  f32x4 acc[4][4];
#pragma unroll
  for (int m = 0; m < 4; m++)
#pragma unroll
    for (int n = 0; n < 4; n++) acc[m][n] = (f32x4){0.f, 0.f, 0.f, 0.f};

  for (int k0 = 0; k0 < Nn; k0 += 64)
    mm_step(Mb, Nn, Mb, Nn, As, Bs, i0, j0, k0, l, w, wr, wc, acc);
  for (int k0 = 0; k0 < KEXT; k0 += 64)
    mm_step(Aext, KEXT, Bext, KEXT, As, Bs, i0, j0, k0, l, w, wr, wc, acc);

#pragma unroll
  for (int m = 0; m < 4; m++) {
#pragma unroll
    for (int n = 0; n < 4; n++) {
#pragma unroll
      for (int q = 0; q < 4; q++) {
        int gi = i0 + wr * 64 + m * 16 + ((l >> 4) << 2) + q;
        int gj = j0 + wc * 64 + n * 16 + (l & 15);
        float v = acc[m][n][q] + mu[gi] * m1[gj] + m1[gi] * mu[gj];
        if (gi == gj) v *= d2[gi];
        out[(size_t)gi * Nn + gj] = v;
      }
    }
  }
}

extern "C" void kernel_launch(void* const* d_in, const int* in_sizes, int n_in,
                              void* d_out, int out_size, void* d_ws, size_t ws_size,
                              hipStream_t stream) {
  const float* x = (const float*)d_in[0];  // [N,D]
  const float* w = (const float*)d_in[1];  // [D]
  const int* ei = (const int*)d_in[2];     // [2,E]
  const int* src = ei;
  const int* dstv = ei + Ee;
  float* out = (float*)d_out;

  // workspace (~61 MB). XcatT (8.5MB) aliases Mb (33.5MB): XcatT dies before M-pass writes Mb.
  unsigned short* Mb = (unsigned short*)d_ws;                       // [4096][4096] bf16
  float* xcat = (float*)d_ws;                                       // [516][4096] f32 (alias)
  unsigned short* aext = (unsigned short*)((char*)d_ws + (size_t)Nn * Nn * 2);  // [4096][1536]
  unsigned short* bext = aext + (size_t)Nn * KEXT;                  // [4096][1536]
  int2* ell = (int2*)(bext + (size_t)Nn * KEXT);                    // WCAP*Nn (2 MB)
  float* sq = (float*)(ell + (size_t)WCAP * Nn);                    // Nn
  float* dis = sq + Nn;                                             // Nn
  float* d2 = dis + Nn;                                             // Nn
  float* mu = d2 + Nn;                                              // Nn
  float* m1 = mu + Nn;                                              // Nn
  int* degi = (int*)(m1 + Nn);                                      // Nn -- zero block start
  int* degrow = degi + Nn;                                          // Nn
  int* slotcnt = degrow + Nn;                                       // Nn
  int* bincnt = slotcnt + Nn;                                       // WCAP+1 -- zero block end
  int* binbase = bincnt + (WCAP + 1);                               // WCAP+1
  int* perm = binbase + (WCAP + 1);                                 // Nn
  int* rnk = perm + Nn;                                             // Nn
  int* wsub = rnk + Nn;                                             // 64

  hipMemsetAsync(ell, 0, (size_t)WCAP * Nn * sizeof(int2), stream);
  hipMemsetAsync(degi, 0, sizeof(int) * (3 * Nn + (WCAP + 1)), stream);

  k_sq<<<Nn, 256, 0, stream>>>(x, w, sq);
  k_count<<<Ee / 256, 256, 0, stream>>>(src, dstv, degi, degrow);
  k_dis<<<Nn / 256, 256, 0, stream>>>(degi, degrow, dis, d2);
  k_hist<<<1, 256, 0, stream>>>(degi, binbase);
  k_scatter<<<Nn / 256, 256, 0, stream>>>(degi, binbase, bincnt, perm, rnk);
  k_wsub<<<1, 64, 0, stream>>>(degi, perm, wsub);
  k_fill_ell<<<(Ee + Nn + 255) / 256, 256, 0, stream>>>(src, dstv, dis, rnk, slotcnt, ell);
  k_xpose<<<dim3(16, 128), 256, 0, stream>>>(x, xcat);
  k_tail<<<Nn / 256, 256, 0, stream>>>(sq, xcat);

  // B-pass: Y = M[X|u|1]; epilogue writes aext=(-2w)Y hi/lo combos, bext=Y hi/lo, mu, m1
  k_appnp<0><<<BCOLS / CT, TPB, Nn * sizeof(float4), stream>>>(xcat, w, nullptr, aext, bext,
                                                               mu, m1, ell, perm, wsub);
  // M-pass: Mb = bf16(APPNP(I))
  k_appnp<1><<<Nn / CT, TPB, Nn * sizeof(float4), stream>>>(nullptr, nullptr, Mb, nullptr,
                                                            nullptr, nullptr, nullptr, ell,
                                                            perm, wsub);
  // out = Mb Mb^T + Aext Bext^T + mu m1^T + m1 mu^T ; diag *= d2
  k_mm<<<dim3(32, 32), 256, 0, stream>>>(Mb, aext, bext, mu, m1, d2, out);
}

// Round 7
// 908.321 us; speedup vs baseline: 1.5769x; 1.0698x over previous
//
#include <hip/hip_runtime.h>
#include <stdint.h>

#define Nn 4096
#define Dd 512
#define Ee 65536
#define HOPS 10
#define TPB 512
#define RPT (Nn / TPB)  // 8 rows per thread
#define CT 4            // columns per block
#define WCAP 64         // ELL slot capacity (max in-degree+1; Poisson(16) max ~38)
#define KEXT 1536       // hi/lo-split extension K: [Phi|Phi|Plo] x [Yhi|Ylo|Yhi]
#define YC 640          // padded col count of Y = [X(512)|u|1|pad...]
#define XK 8192         // xb row length: [hi(4096) | lo(4096)]

typedef short bf16x8 __attribute__((ext_vector_type(8)));
typedef float f32x4 __attribute__((ext_vector_type(4)));

// ---------------- helpers ----------------
__device__ __forceinline__ unsigned short bf16r(float x) {  // RNE fp32->bf16
  unsigned int b = __float_as_uint(x);
  return (unsigned short)((b + 0x7FFFu + ((b >> 16) & 1u)) >> 16);
}
__device__ __forceinline__ float ubf(unsigned short h) {
  return __uint_as_float(((unsigned int)h) << 16);
}
__device__ __forceinline__ void gld16(const unsigned short* g, unsigned short* lds) {
  __builtin_amdgcn_global_load_lds(
      (const __attribute__((address_space(1))) unsigned int*)g,
      (__attribute__((address_space(3))) unsigned int*)lds, 16, 0, 0);
}

// ---------------- sq[i] = sum_d w_d * x[i,d]^2 ----------------
__global__ __launch_bounds__(256) void k_sq(const float* __restrict__ x,
                                            const float* __restrict__ w,
                                            float* __restrict__ sq) {
  int row = blockIdx.x;
  int tid = threadIdx.x;
  const float* xr = x + (size_t)row * Dd;
  float partial = 0.f;
  for (int d = tid; d < Dd; d += 256) {
    float xv = xr[d];
    partial += xv * xv * w[d];
  }
  for (int off = 32; off >= 1; off >>= 1) partial += __shfl_down(partial, off, 64);
  __shared__ float red[4];
  int wv = tid >> 6, ln = tid & 63;
  if (ln == 0) red[wv] = partial;
  __syncthreads();
  if (tid == 0) sq[row] = red[0] + red[1] + red[2] + red[3];
}

// ---------------- degree counting ----------------
__global__ void k_count(const int* __restrict__ src, const int* __restrict__ dst,
                        int* __restrict__ degi, int* __restrict__ degrow) {
  int e = blockIdx.x * blockDim.x + threadIdx.x;
  if (e < Ee) {
    atomicAdd(&degi[dst[e]], 1);
    atomicAdd(&degrow[src[e]], 1);
  }
}

// ---------------- dis = (deg_in+1)^-0.5 ; d2 = 1/(deg_row+1) ----------------
__global__ void k_dis(const int* __restrict__ degi, const int* __restrict__ degrow,
                      float* __restrict__ dis, float* __restrict__ d2) {
  int i = blockIdx.x * 256 + threadIdx.x;
  dis[i] = rsqrtf((float)(degi[i] + 1));
  d2[i] = 1.0f / ((float)degrow[i] + 1.0f);
}

// ---------------- histogram of (deg_in+1) + exclusive prefix -> binbase ----------------
__global__ void k_hist(const int* __restrict__ degi, int* __restrict__ binbase) {
  __shared__ int h[WCAP + 1];
  int t = threadIdx.x;
  if (t <= WCAP) h[t] = 0;
  __syncthreads();
  for (int i = t; i < Nn; i += 256) {
    int d = degi[i] + 1;
    if (d > WCAP) d = WCAP;
    atomicAdd(&h[d], 1);
  }
  __syncthreads();
  if (t == 0) {
    int run = 0;
    for (int b = 0; b <= WCAP; b++) { int c = h[b]; binbase[b] = run; run += c; }
  }
}

// ---------------- counting-sort scatter: perm (sorted pos -> row), rnk (row -> pos) ----------------
__global__ void k_scatter(const int* __restrict__ degi, const int* __restrict__ binbase,
                          int* __restrict__ bincnt, int* __restrict__ perm,
                          int* __restrict__ rnk) {
  int i = blockIdx.x * 256 + threadIdx.x;
  int d = degi[i] + 1;
  if (d > WCAP) d = WCAP;
  int pos = binbase[d] + atomicAdd(&bincnt[d], 1);
  perm[pos] = i;
  rnk[i] = pos;
}

// ---------------- per-(wave,chain) slot bounds ----------------
__global__ void k_wsub(const int* __restrict__ degi, const int* __restrict__ perm,
                       int* __restrict__ wsub) {
  int t = threadIdx.x;
  int d = degi[perm[t * 64 + 63]] + 1;
  wsub[t] = d > WCAP ? WCAP : d;
}

// ---------------- ELL fill (slot-major, sorted-position indexed) ----------------
__global__ void k_fill_ell(const int* __restrict__ src, const int* __restrict__ dst,
                           const float* __restrict__ dis, const int* __restrict__ rnk,
                           int* __restrict__ slot, int2* __restrict__ ell) {
  int i = blockIdx.x * blockDim.x + threadIdx.x;
  if (i < Ee) {
    int s = src[i], d = dst[i];
    int p = atomicAdd(&slot[d], 1);
    if (p < WCAP) ell[(size_t)p * Nn + rnk[d]] = make_int2(s, __float_as_int(dis[s] * dis[d]));
  } else if (i < Ee + Nn) {
    int v = i - Ee;
    int p = atomicAdd(&slot[v], 1);
    if (p < WCAP) ell[(size_t)p * Nn + rnk[v]] = make_int2(v, __float_as_int(dis[v] * dis[v]));
  }
}

// ---------------- xb[c][k] = bf16 hi/lo of X^T: rows c = feature cols, k = nodes ----------------
__global__ __launch_bounds__(256) void k_xpose(const float* __restrict__ x,
                                               unsigned short* __restrict__ xb) {
  __shared__ float tile[32][33];
  int cx = blockIdx.x, rx = blockIdx.y;
  int t = threadIdx.x, txc = t & 31, tyc = t >> 5;
#pragma unroll
  for (int i = 0; i < 4; i++) {
    int a = tyc + i * 8;
    tile[a][txc] = x[(size_t)(rx * 32 + a) * Dd + cx * 32 + txc];
  }
  __syncthreads();
#pragma unroll
  for (int i = 0; i < 4; i++) {
    int a = tyc + i * 8;
    int c = cx * 32 + a;
    float v = tile[txc][a];
    unsigned short hi = bf16r(v);
    xb[(size_t)c * XK + rx * 32 + txc] = hi;
    xb[(size_t)c * XK + Nn + rx * 32 + txc] = bf16r(v - ubf(hi));
  }
}

// ---------------- xb tail rows: u (=sq) at c=512, ones at c=513 ----------------
__global__ void k_tail(const float* __restrict__ sq, unsigned short* __restrict__ xb) {
  int r = blockIdx.x * 256 + threadIdx.x;
  float v = sq[r];
  unsigned short hi = bf16r(v);
  xb[(size_t)512 * XK + r] = hi;
  xb[(size_t)512 * XK + Nn + r] = bf16r(v - ubf(hi));
  xb[(size_t)513 * XK + r] = bf16r(1.0f);
  xb[(size_t)513 * XK + Nn + r] = 0;
}

// ---------------- fused 10-hop APPNP(I) -> Mb = bf16(M); h resident in LDS ----------------
__global__ __launch_bounds__(TPB, 4) void k_appnp(unsigned short* __restrict__ mb,
                                                  const int2* __restrict__ ell,
                                                  const int* __restrict__ perm,
                                                  const int* __restrict__ wsub) {
  extern __shared__ float4 h4[];  // Nn entries = 64 KB
  int j0 = blockIdx.x * CT;
  int tid = threadIdx.x;
  int wv = tid >> 6, ln = tid & 63;
  int qb = wv * 512 + ln;

#pragma unroll
  for (int rr = 0; rr < RPT; rr++) {
    int r = tid + rr * TPB;
    float4 v;
    v.x = (r == j0 + 0) ? 1.f : 0.f;
    v.y = (r == j0 + 1) ? 1.f : 0.f;
    v.z = (r == j0 + 2) ? 1.f : 0.f;
    v.w = (r == j0 + 3) ? 1.f : 0.f;
    h4[r] = v;
  }

  int ws[RPT];
#pragma unroll
  for (int rr = 0; rr < RPT; rr++)
    ws[rr] = __builtin_amdgcn_readfirstlane(wsub[wv * 8 + rr]);
  const int Wv = ws[RPT - 1];

  int rp[RPT];
#pragma unroll
  for (int rr = 0; rr < RPT; rr++) rp[rr] = perm[qb + rr * 64];

  __syncthreads();
  float4 x0r[RPT];
#pragma unroll
  for (int rr = 0; rr < RPT; rr++) x0r[rr] = h4[rp[rr]];

  float4 acc[RPT];
  for (int it = 0; it < HOPS; it++) {
    int2 cur[RPT];
#pragma unroll
    for (int rr = 0; rr < RPT; rr++) cur[rr] = ell[qb + rr * 64];
#pragma unroll
    for (int rr = 0; rr < RPT; rr++) acc[rr] = x0r[rr];
    for (int s = 0; s < Wv; s++) {
      int sn = s + 1;
      int2 nxt[RPT];
#pragma unroll
      for (int rr = 0; rr < RPT; rr++)
        if (sn < ws[rr]) nxt[rr] = ell[(size_t)sn * Nn + qb + rr * 64];
#pragma unroll
      for (int rr = 0; rr < RPT; rr++)
        if (s < ws[rr]) {
          float vv = __int_as_float(cur[rr].y);
          float4 hu = h4[cur[rr].x];
          acc[rr].x = fmaf(vv, hu.x, acc[rr].x);
          acc[rr].y = fmaf(vv, hu.y, acc[rr].y);
          acc[rr].z = fmaf(vv, hu.z, acc[rr].z);
          acc[rr].w = fmaf(vv, hu.w, acc[rr].w);
        }
#pragma unroll
      for (int rr = 0; rr < RPT; rr++)
        if (sn < ws[rr]) cur[rr] = nxt[rr];
    }
#pragma unroll
    for (int rr = 0; rr < RPT; rr++) {
      acc[rr].x *= 0.5f; acc[rr].y *= 0.5f; acc[rr].z *= 0.5f; acc[rr].w *= 0.5f;
    }
    __syncthreads();
#pragma unroll
    for (int rr = 0; rr < RPT; rr++) h4[rp[rr]] = acc[rr];
    __syncthreads();
  }

#pragma unroll
  for (int rr = 0; rr < RPT; rr++) {
    int r = tid + rr * TPB;
    float4 a = h4[r];
    ushort4 o = make_ushort4(bf16r(a.x), bf16r(a.y), bf16r(a.z), bf16r(a.w));
    *(ushort4*)&mb[(size_t)r * Nn + j0] = o;
  }
}

// ---------------- shared MFMA tile step (proven in round 6) ----------------
// 128x128 tile, BK=64; LDS [128][64] ushort, chunk XOR-swizzle slot = c ^ (row&7)
// applied on the pre-swizzled GLOBAL source (LDS dest of global_load_lds stays linear).
__device__ __forceinline__ void mm_step(const unsigned short* __restrict__ Ap, int lda,
                                        const unsigned short* __restrict__ Bp, int ldb,
                                        unsigned short* As, unsigned short* Bs,
                                        int i0, int j0, int k0, int l, int w, int wr,
                                        int wc, f32x4 acc[4][4]) {
  int rsub = w * 8 + (l >> 3);              // row within 32-row round
  int scg = ((l & 7) ^ (l >> 3)) * 8;       // pre-swizzled source chunk offset (ushorts)
#pragma unroll
  for (int r = 0; r < 4; r++) {
    int row = r * 32 + rsub;
    gld16(Ap + (size_t)(i0 + row) * lda + k0 + scg, As + (r * 32 + w * 8) * 64);
    gld16(Bp + (size_t)(j0 + row) * ldb + k0 + scg, Bs + (r * 32 + w * 8) * 64);
  }
  __syncthreads();
#pragma unroll
  for (int q = 0; q < 2; q++) {
    bf16x8 af[4], bg[4];
#pragma unroll
    for (int m = 0; m < 4; m++) {
      int ar = wr * 64 + m * 16 + (l & 15);
      af[m] = *(const bf16x8*)(As + ar * 64 + ((((l >> 4) + 4 * q) ^ (ar & 7)) * 8));
      int br = wc * 64 + m * 16 + (l & 15);
      bg[m] = *(const bf16x8*)(Bs + br * 64 + ((((l >> 4) + 4 * q) ^ (br & 7)) * 8));
    }
#pragma unroll
    for (int m = 0; m < 4; m++)
#pragma unroll
      for (int n = 0; n < 4; n++)
        acc[m][n] = __builtin_amdgcn_mfma_f32_16x16x32_bf16(af[m], bg[n], acc[m][n], 0, 0, 0);
  }
  __syncthreads();
}

// ---------------- Y = Mb * xb^T (K = 4096 hi + 4096 lo); epilogue -> aext/bext/mu/m1 ----------------
__global__ __launch_bounds__(256) void k_ymm(const unsigned short* __restrict__ Mb,
                                             const unsigned short* __restrict__ xb,
                                             const float* __restrict__ wp,
                                             unsigned short* __restrict__ aext,
                                             unsigned short* __restrict__ bext,
                                             float* __restrict__ mu,
                                             float* __restrict__ m1) {
  __shared__ unsigned short As[128 * 64];
  __shared__ unsigned short Bs[128 * 64];
  int i0 = blockIdx.y * 128, j0 = blockIdx.x * 128;
  int tid = threadIdx.x, l = tid & 63, w = tid >> 6;
  int wr = w >> 1, wc = w & 1;
  f32x4 acc[4][4];
#pragma unroll
  for (int m = 0; m < 4; m++)
#pragma unroll
    for (int n = 0; n < 4; n++) acc[m][n] = (f32x4){0.f, 0.f, 0.f, 0.f};

  // segment 0: Xhi (xb cols 0..4095); segment 1: Xlo (xb cols 4096..8191)
  for (int k0 = 0; k0 < Nn; k0 += 64)
    mm_step(Mb, Nn, xb, XK, As, Bs, i0, j0, k0, l, w, wr, wc, acc);
  for (int k0 = 0; k0 < Nn; k0 += 64)
    mm_step(Mb, Nn, xb + Nn, XK, As, Bs, i0, j0, k0, l, w, wr, wc, acc);

#pragma unroll
  for (int m = 0; m < 4; m++) {
#pragma unroll
    for (int n = 0; n < 4; n++) {
#pragma unroll
      for (int q = 0; q < 4; q++) {
        int gi = i0 + wr * 64 + m * 16 + ((l >> 4) << 2) + q;
        int gj = j0 + wc * 64 + n * 16 + (l & 15);
        float y = acc[m][n][q];
        if (gj < 512) {
          unsigned short yhi = bf16r(y);
          unsigned short ylo = bf16r(y - ubf(yhi));
          float p = -2.f * wp[gj] * y;
          unsigned short phi = bf16r(p);
          unsigned short plo = bf16r(p - ubf(phi));
          bext[(size_t)gi * KEXT + gj] = yhi;
          bext[(size_t)gi * KEXT + 512 + gj] = ylo;
          bext[(size_t)gi * KEXT + 1024 + gj] = yhi;
          aext[(size_t)gi * KEXT + gj] = phi;
          aext[(size_t)gi * KEXT + 512 + gj] = phi;
          aext[(size_t)gi * KEXT + 1024 + gj] = plo;
        } else if (gj == 512) {
          mu[gi] = y;
        } else if (gj == 513) {
          m1[gi] = y;
        }
      }
    }
  }
}

// ---------------- out = Mb Mb^T + Aext Bext^T + mu m1^T + m1 mu^T ; diag *= d2 ----------------
__global__ __launch_bounds__(256) void k_mm(const unsigned short* __restrict__ Mb,
                                            const unsigned short* __restrict__ Aext,
                                            const unsigned short* __restrict__ Bext,
                                            const float* __restrict__ mu,
                                            const float* __restrict__ m1,
                                            const float* __restrict__ d2,
                                            float* __restrict__ out) {
  __shared__ unsigned short As[128 * 64];
  __shared__ unsigned short Bs[128 * 64];
  int lid = blockIdx.y * 32 + blockIdx.x;
  int swz = (lid & 7) * 128 + (lid >> 3);  // 1024 % 8 == 0 -> bijective
  int i0 = (swz >> 5) * 128, j0 = (swz & 31) * 128;
  int tid = threadIdx.x, l = tid & 63, w = tid >> 6;
  int wr = w >> 1, wc = w & 1;
  f32x4 acc[4][4];
#pragma unroll
  for (int m = 0; m < 4; m++)
#pragma unroll
    for (int n = 0; n < 4; n++) acc[m][n] = (f32x4){0.f, 0.f, 0.f, 0.f};

  for (int k0 = 0; k0 < Nn; k0 += 64)
    mm_step(Mb, Nn, Mb, Nn, As, Bs, i0, j0, k0, l, w, wr, wc, acc);
  for (int k0 = 0; k0 < KEXT; k0 += 64)
    mm_step(Aext, KEXT, Bext, KEXT, As, Bs, i0, j0, k0, l, w, wr, wc, acc);

#pragma unroll
  for (int m = 0; m < 4; m++) {
#pragma unroll
    for (int n = 0; n < 4; n++) {
#pragma unroll
      for (int q = 0; q < 4; q++) {
        int gi = i0 + wr * 64 + m * 16 + ((l >> 4) << 2) + q;
        int gj = j0 + wc * 64 + n * 16 + (l & 15);
        float v = acc[m][n][q] + mu[gi] * m1[gj] + m1[gi] * mu[gj];
        if (gi == gj) v *= d2[gi];
        out[(size_t)gi * Nn + gj] = v;
      }
    }
  }
}

extern "C" void kernel_launch(void* const* d_in, const int* in_sizes, int n_in,
                              void* d_out, int out_size, void* d_ws, size_t ws_size,
                              hipStream_t stream) {
  const float* x = (const float*)d_in[0];  // [N,D]
  const float* w = (const float*)d_in[1];  // [D]
  const int* ei = (const int*)d_in[2];     // [2,E]
  const int* src = ei;
  const int* dstv = ei + Ee;
  float* out = (float*)d_out;

  // workspace (~71.4 MB)
  unsigned short* Mb = (unsigned short*)d_ws;                       // [4096][4096] bf16 (33.5MB)
  unsigned short* aext = Mb + (size_t)Nn * Nn;                      // [4096][1536] (12.6MB)
  unsigned short* bext = aext + (size_t)Nn * KEXT;                  // [4096][1536] (12.6MB)
  unsigned short* xb = bext + (size_t)Nn * KEXT;                    // [640][8192] (10.5MB)
  int2* ell = (int2*)(xb + (size_t)YC * XK);                        // WCAP*Nn (2MB)
  float* sq = (float*)(ell + (size_t)WCAP * Nn);                    // Nn
  float* dis = sq + Nn;                                             // Nn
  float* d2 = dis + Nn;                                             // Nn
  float* mu = d2 + Nn;                                              // Nn
  float* m1 = mu + Nn;                                              // Nn
  int* degi = (int*)(m1 + Nn);                                      // Nn -- zero block start
  int* degrow = degi + Nn;                                          // Nn
  int* slotcnt = degrow + Nn;                                       // Nn
  int* bincnt = slotcnt + Nn;                                       // WCAP+1 -- zero block end
  int* binbase = bincnt + (WCAP + 1);                               // WCAP+1
  int* perm = binbase + (WCAP + 1);                                 // Nn
  int* rnk = perm + Nn;                                             // Nn
  int* wsub = rnk + Nn;                                             // 64

  hipMemsetAsync(ell, 0, (size_t)WCAP * Nn * sizeof(int2), stream);
  hipMemsetAsync(degi, 0, sizeof(int) * (3 * Nn + (WCAP + 1)), stream);
  hipMemsetAsync(xb, 0, (size_t)YC * XK * sizeof(unsigned short), stream);

  k_sq<<<Nn, 256, 0, stream>>>(x, w, sq);
  k_count<<<Ee / 256, 256, 0, stream>>>(src, dstv, degi, degrow);
  k_dis<<<Nn / 256, 256, 0, stream>>>(degi, degrow, dis, d2);
  k_hist<<<1, 256, 0, stream>>>(degi, binbase);
  k_scatter<<<Nn / 256, 256, 0, stream>>>(degi, binbase, bincnt, perm, rnk);
  k_wsub<<<1, 64, 0, stream>>>(degi, perm, wsub);
  k_fill_ell<<<(Ee + Nn + 255) / 256, 256, 0, stream>>>(src, dstv, dis, rnk, slotcnt, ell);
  k_xpose<<<dim3(16, 128), 256, 0, stream>>>(x, xb);
  k_tail<<<Nn / 256, 256, 0, stream>>>(sq, xb);

  // M-pass: Mb = bf16(APPNP(I))  -- the one remaining gather sweep
  k_appnp<<<Nn / CT, TPB, Nn * sizeof(float4), stream>>>(Mb, ell, perm, wsub);
  // Y = Mb * xb^T (hi+lo) ; epilogue builds aext/bext hi/lo splits + mu/m1
  k_ymm<<<dim3(YC / 128, Nn / 128), 256, 0, stream>>>(Mb, xb, w, aext, bext, mu, m1);
  // out = Mb Mb^T + Aext Bext^T + rank-2 ; diag *= d2
  k_mm<<<dim3(32, 32), 256, 0, stream>>>(Mb, aext, bext, mu, m1, d2, out);
}

// Round 8
// 891.659 us; speedup vs baseline: 1.6063x; 1.0187x over previous
//
#include <hip/hip_runtime.h>
#include <stdint.h>

#define Nn 4096
#define Dd 512
#define Ee 65536
#define HOPS 10
#define TPB 512
#define RPT (Nn / TPB)  // 8 rows per thread
#define CT8 8           // packed bf16 columns per block (8 x bf16 = 16B LDS entry)
#define WCAP 64         // ELL slot capacity (max in-degree+1; Poisson(16) max ~38)
#define KEXT 1536       // hi/lo-split extension K: [Phi|Phi|Plo] x [Yhi|Ylo|Yhi]
#define YC 640          // padded col count of Y = [X(512)|u|1|pad...]
#define XK 8192         // xb row length: [hi(4096) | lo(4096)]

typedef short bf16x8 __attribute__((ext_vector_type(8)));
typedef float f32x4 __attribute__((ext_vector_type(4)));

// ---------------- helpers ----------------
__device__ __forceinline__ unsigned short bf16r(float x) {  // RNE fp32->bf16
  unsigned int b = __float_as_uint(x);
  return (unsigned short)((b + 0x7FFFu + ((b >> 16) & 1u)) >> 16);
}
__device__ __forceinline__ unsigned int pkbf(float lo, float hi) {  // 2 cols -> 1 uint
  return (unsigned int)bf16r(lo) | ((unsigned int)bf16r(hi) << 16);
}
__device__ __forceinline__ float ubf(unsigned short h) {
  return __uint_as_float(((unsigned int)h) << 16);
}
__device__ __forceinline__ void gld16(const unsigned short* g, unsigned short* lds) {
  __builtin_amdgcn_global_load_lds(
      (const __attribute__((address_space(1))) unsigned int*)g,
      (__attribute__((address_space(3))) unsigned int*)lds, 16, 0, 0);
}

// ---------------- sq[i] = sum_d w_d * x[i,d]^2 ----------------
__global__ __launch_bounds__(256) void k_sq(const float* __restrict__ x,
                                            const float* __restrict__ w,
                                            float* __restrict__ sq) {
  int row = blockIdx.x;
  int tid = threadIdx.x;
  const float* xr = x + (size_t)row * Dd;
  float partial = 0.f;
  for (int d = tid; d < Dd; d += 256) {
    float xv = xr[d];
    partial += xv * xv * w[d];
  }
  for (int off = 32; off >= 1; off >>= 1) partial += __shfl_down(partial, off, 64);
  __shared__ float red[4];
  int wv = tid >> 6, ln = tid & 63;
  if (ln == 0) red[wv] = partial;
  __syncthreads();
  if (tid == 0) sq[row] = red[0] + red[1] + red[2] + red[3];
}

// ---------------- degree counting ----------------
__global__ void k_count(const int* __restrict__ src, const int* __restrict__ dst,
                        int* __restrict__ degi, int* __restrict__ degrow) {
  int e = blockIdx.x * blockDim.x + threadIdx.x;
  if (e < Ee) {
    atomicAdd(&degi[dst[e]], 1);
    atomicAdd(&degrow[src[e]], 1);
  }
}

// ---------------- dis = (deg_in+1)^-0.5 ; d2 = 1/(deg_row+1) ----------------
__global__ void k_dis(const int* __restrict__ degi, const int* __restrict__ degrow,
                      float* __restrict__ dis, float* __restrict__ d2) {
  int i = blockIdx.x * 256 + threadIdx.x;
  dis[i] = rsqrtf((float)(degi[i] + 1));
  d2[i] = 1.0f / ((float)degrow[i] + 1.0f);
}

// ---------------- histogram of (deg_in+1) + exclusive prefix -> binbase ----------------
__global__ void k_hist(const int* __restrict__ degi, int* __restrict__ binbase) {
  __shared__ int h[WCAP + 1];
  int t = threadIdx.x;
  if (t <= WCAP) h[t] = 0;
  __syncthreads();
  for (int i = t; i < Nn; i += 256) {
    int d = degi[i] + 1;
    if (d > WCAP) d = WCAP;
    atomicAdd(&h[d], 1);
  }
  __syncthreads();
  if (t == 0) {
    int run = 0;
    for (int b = 0; b <= WCAP; b++) { int c = h[b]; binbase[b] = run; run += c; }
  }
}

// ---------------- counting-sort scatter: perm (sorted pos -> row), rnk (row -> pos) ----------------
__global__ void k_scatter(const int* __restrict__ degi, const int* __restrict__ binbase,
                          int* __restrict__ bincnt, int* __restrict__ perm,
                          int* __restrict__ rnk) {
  int i = blockIdx.x * 256 + threadIdx.x;
  int d = degi[i] + 1;
  if (d > WCAP) d = WCAP;
  int pos = binbase[d] + atomicAdd(&bincnt[d], 1);
  perm[pos] = i;
  rnk[i] = pos;
}

// ---------------- per-(wave,chain) slot bounds ----------------
__global__ void k_wsub(const int* __restrict__ degi, const int* __restrict__ perm,
                       int* __restrict__ wsub) {
  int t = threadIdx.x;
  int d = degi[perm[t * 64 + 63]] + 1;
  wsub[t] = d > WCAP ? WCAP : d;
}

// ---------------- ELL fill (slot-major, sorted-position indexed) ----------------
__global__ void k_fill_ell(const int* __restrict__ src, const int* __restrict__ dst,
                           const float* __restrict__ dis, const int* __restrict__ rnk,
                           int* __restrict__ slot, int2* __restrict__ ell) {
  int i = blockIdx.x * blockDim.x + threadIdx.x;
  if (i < Ee) {
    int s = src[i], d = dst[i];
    int p = atomicAdd(&slot[d], 1);
    if (p < WCAP) ell[(size_t)p * Nn + rnk[d]] = make_int2(s, __float_as_int(dis[s] * dis[d]));
  } else if (i < Ee + Nn) {
    int v = i - Ee;
    int p = atomicAdd(&slot[v], 1);
    if (p < WCAP) ell[(size_t)p * Nn + rnk[v]] = make_int2(v, __float_as_int(dis[v] * dis[v]));
  }
}

// ---------------- xb[c][k] = bf16 hi/lo of X^T: rows c = feature cols, k = nodes ----------------
__global__ __launch_bounds__(256) void k_xpose(const float* __restrict__ x,
                                               unsigned short* __restrict__ xb) {
  __shared__ float tile[32][33];
  int cx = blockIdx.x, rx = blockIdx.y;
  int t = threadIdx.x, txc = t & 31, tyc = t >> 5;
#pragma unroll
  for (int i = 0; i < 4; i++) {
    int a = tyc + i * 8;
    tile[a][txc] = x[(size_t)(rx * 32 + a) * Dd + cx * 32 + txc];
  }
  __syncthreads();
#pragma unroll
  for (int i = 0; i < 4; i++) {
    int a = tyc + i * 8;
    int c = cx * 32 + a;
    float v = tile[txc][a];
    unsigned short hi = bf16r(v);
    xb[(size_t)c * XK + rx * 32 + txc] = hi;
    xb[(size_t)c * XK + Nn + rx * 32 + txc] = bf16r(v - ubf(hi));
  }
}

// ---------------- xb tail rows: u (=sq) at c=512, ones at c=513 ----------------
__global__ void k_tail(const float* __restrict__ sq, unsigned short* __restrict__ xb) {
  int r = blockIdx.x * 256 + threadIdx.x;
  float v = sq[r];
  unsigned short hi = bf16r(v);
  xb[(size_t)512 * XK + r] = hi;
  xb[(size_t)512 * XK + Nn + r] = bf16r(v - ubf(hi));
  xb[(size_t)513 * XK + r] = bf16r(1.0f);
  xb[(size_t)513 * XK + Nn + r] = 0;
}

// ---------------- fused 10-hop APPNP(I) -> Mb = bf16(M); h packed bf16x8 in LDS ----------------
// 8 columns per block (vs 4): each ds_read_b128 gather now feeds 8 columns -> half the
// blocks, half the LDS-gather issue + half the ELL traffic. h state bf16-rounded per hop:
// safe since ||0.5*Ahat|| <= 0.5 damps rounding geometrically (total < 2 ulp_bf16 rel).
// Unpack: col pair per uint -> u<<16 (even) / u & 0xFFFF0000 (odd), 1 VALU per col.
__global__ __launch_bounds__(TPB, 4) void k_appnp(unsigned short* __restrict__ mb,
                                                  const int2* __restrict__ ell,
                                                  const int* __restrict__ perm,
                                                  const int* __restrict__ wsub) {
  extern __shared__ uint4 h4u[];  // Nn entries = 64 KB (8 bf16 cols packed)
  int j0 = blockIdx.x * CT8;
  int tid = threadIdx.x;
  int wv = tid >> 6, ln = tid & 63;
  int qb = wv * 512 + ln;

  // init h = identity columns j0..j0+7 (bf16(1.0) = 0x3F80 in the matching half-word)
#pragma unroll
  for (int rr = 0; rr < RPT; rr++) {
    int r = tid + rr * TPB;
    uint4 v = make_uint4(0u, 0u, 0u, 0u);
    int c = r - j0;
    if (c >= 0 && c < 8) {
      unsigned int one = (c & 1) ? 0x3F800000u : 0x00003F80u;
      if ((c >> 1) == 0) v.x = one;
      else if ((c >> 1) == 1) v.y = one;
      else if ((c >> 1) == 2) v.z = one;
      else v.w = one;
    }
    h4u[r] = v;
  }

  int ws[RPT];
#pragma unroll
  for (int rr = 0; rr < RPT; rr++)
    ws[rr] = __builtin_amdgcn_readfirstlane(wsub[wv * 8 + rr]);
  const int Wv = ws[RPT - 1];

  int rp[RPT], x0c[RPT];
#pragma unroll
  for (int rr = 0; rr < RPT; rr++) {
    rp[rr] = perm[qb + rr * 64];
    int c = rp[rr] - j0;
    x0c[rr] = (c >= 0 && c < 8) ? c : -1;
  }
  __syncthreads();

  for (int it = 0; it < HOPS; it++) {
    int2 cur[RPT];
#pragma unroll
    for (int rr = 0; rr < RPT; rr++) cur[rr] = ell[qb + rr * 64];
    float acc[RPT][8];
#pragma unroll
    for (int rr = 0; rr < RPT; rr++)
#pragma unroll
      for (int c = 0; c < 8; c++) acc[rr][c] = (x0c[rr] == c) ? 1.0f : 0.0f;
    for (int s = 0; s < Wv; s++) {
      int sn = s + 1;
      int2 nxt[RPT];
#pragma unroll
      for (int rr = 0; rr < RPT; rr++)
        if (sn < ws[rr]) nxt[rr] = ell[(size_t)sn * Nn + qb + rr * 64];
#pragma unroll
      for (int rr = 0; rr < RPT; rr++)
        if (s < ws[rr]) {
          float vv = __int_as_float(cur[rr].y);
          uint4 hu = h4u[cur[rr].x];
          acc[rr][0] = fmaf(vv, __uint_as_float(hu.x << 16), acc[rr][0]);
          acc[rr][1] = fmaf(vv, __uint_as_float(hu.x & 0xFFFF0000u), acc[rr][1]);
          acc[rr][2] = fmaf(vv, __uint_as_float(hu.y << 16), acc[rr][2]);
          acc[rr][3] = fmaf(vv, __uint_as_float(hu.y & 0xFFFF0000u), acc[rr][3]);
          acc[rr][4] = fmaf(vv, __uint_as_float(hu.z << 16), acc[rr][4]);
          acc[rr][5] = fmaf(vv, __uint_as_float(hu.z & 0xFFFF0000u), acc[rr][5]);
          acc[rr][6] = fmaf(vv, __uint_as_float(hu.w << 16), acc[rr][6]);
          acc[rr][7] = fmaf(vv, __uint_as_float(hu.w & 0xFFFF0000u), acc[rr][7]);
        }
#pragma unroll
      for (int rr = 0; rr < RPT; rr++)
        if (sn < ws[rr]) cur[rr] = nxt[rr];
    }
    __syncthreads();
#pragma unroll
    for (int rr = 0; rr < RPT; rr++) {
      uint4 v;
      v.x = pkbf(0.5f * acc[rr][0], 0.5f * acc[rr][1]);
      v.y = pkbf(0.5f * acc[rr][2], 0.5f * acc[rr][3]);
      v.z = pkbf(0.5f * acc[rr][4], 0.5f * acc[rr][5]);
      v.w = pkbf(0.5f * acc[rr][6], 0.5f * acc[rr][7]);
      h4u[rp[rr]] = v;
    }
    __syncthreads();
  }

  // Mb[r][j0..j0+7] = packed h row (already bf16), coalesced 16B stores
#pragma unroll
  for (int rr = 0; rr < RPT; rr++) {
    int r = tid + rr * TPB;
    *(uint4*)&mb[(size_t)r * Nn + j0] = h4u[r];
  }
}

// ---------------- shared MFMA tile step (proven in rounds 6-7) ----------------
// 128x128 tile, BK=64; LDS [128][64] ushort, chunk XOR-swizzle slot = c ^ (row&7)
// applied on the pre-swizzled GLOBAL source (LDS dest of global_load_lds stays linear).
__device__ __forceinline__ void mm_step(const unsigned short* __restrict__ Ap, int lda,
                                        const unsigned short* __restrict__ Bp, int ldb,
                                        unsigned short* As, unsigned short* Bs,
                                        int i0, int j0, int k0, int l, int w, int wr,
                                        int wc, f32x4 acc[4][4]) {
  int rsub = w * 8 + (l >> 3);              // row within 32-row round
  int scg = ((l & 7) ^ (l >> 3)) * 8;       // pre-swizzled source chunk offset (ushorts)
#pragma unroll
  for (int r = 0; r < 4; r++) {
    int row = r * 32 + rsub;
    gld16(Ap + (size_t)(i0 + row) * lda + k0 + scg, As + (r * 32 + w * 8) * 64);
    gld16(Bp + (size_t)(j0 + row) * ldb + k0 + scg, Bs + (r * 32 + w * 8) * 64);
  }
  __syncthreads();
#pragma unroll
  for (int q = 0; q < 2; q++) {
    bf16x8 af[4], bg[4];
#pragma unroll
    for (int m = 0; m < 4; m++) {
      int ar = wr * 64 + m * 16 + (l & 15);
      af[m] = *(const bf16x8*)(As + ar * 64 + ((((l >> 4) + 4 * q) ^ (ar & 7)) * 8));
      int br = wc * 64 + m * 16 + (l & 15);
      bg[m] = *(const bf16x8*)(Bs + br * 64 + ((((l >> 4) + 4 * q) ^ (br & 7)) * 8));
    }
#pragma unroll
    for (int m = 0; m < 4; m++)
#pragma unroll
      for (int n = 0; n < 4; n++)
        acc[m][n] = __builtin_amdgcn_mfma_f32_16x16x32_bf16(af[m], bg[n], acc[m][n], 0, 0, 0);
  }
  __syncthreads();
}

// ---------------- Y = Mb * xb^T (K = 4096 hi + 4096 lo); epilogue -> aext/bext/mu/m1 ----------------
__global__ __launch_bounds__(256) void k_ymm(const unsigned short* __restrict__ Mb,
                                             const unsigned short* __restrict__ xb,
                                             const float* __restrict__ wp,
                                             unsigned short* __restrict__ aext,
                                             unsigned short* __restrict__ bext,
                                             float* __restrict__ mu,
                                             float* __restrict__ m1) {
  __shared__ unsigned short As[128 * 64];
  __shared__ unsigned short Bs[128 * 64];
  int i0 = blockIdx.y * 128, j0 = blockIdx.x * 128;
  int tid = threadIdx.x, l = tid & 63, w = tid >> 6;
  int wr = w >> 1, wc = w & 1;
  f32x4 acc[4][4];
#pragma unroll
  for (int m = 0; m < 4; m++)
#pragma unroll
    for (int n = 0; n < 4; n++) acc[m][n] = (f32x4){0.f, 0.f, 0.f, 0.f};

  // segment 0: Xhi (xb cols 0..4095); segment 1: Xlo (xb cols 4096..8191)
  for (int k0 = 0; k0 < Nn; k0 += 64)
    mm_step(Mb, Nn, xb, XK, As, Bs, i0, j0, k0, l, w, wr, wc, acc);
  for (int k0 = 0; k0 < Nn; k0 += 64)
    mm_step(Mb, Nn, xb + Nn, XK, As, Bs, i0, j0, k0, l, w, wr, wc, acc);

#pragma unroll
  for (int m = 0; m < 4; m++) {
#pragma unroll
    for (int n = 0; n < 4; n++) {
#pragma unroll
      for (int q = 0; q < 4; q++) {
        int gi = i0 + wr * 64 + m * 16 + ((l >> 4) << 2) + q;
        int gj = j0 + wc * 64 + n * 16 + (l & 15);
        float y = acc[m][n][q];
        if (gj < 512) {
          unsigned short yhi = bf16r(y);
          unsigned short ylo = bf16r(y - ubf(yhi));
          float p = -2.f * wp[gj] * y;
          unsigned short phi = bf16r(p);
          unsigned short plo = bf16r(p - ubf(phi));
          bext[(size_t)gi * KEXT + gj] = yhi;
          bext[(size_t)gi * KEXT + 512 + gj] = ylo;
          bext[(size_t)gi * KEXT + 1024 + gj] = yhi;
          aext[(size_t)gi * KEXT + gj] = phi;
          aext[(size_t)gi * KEXT + 512 + gj] = phi;
          aext[(size_t)gi * KEXT + 1024 + gj] = plo;
        } else if (gj == 512) {
          mu[gi] = y;
        } else if (gj == 513) {
          m1[gi] = y;
        }
      }
    }
  }
}

// ---------------- out = Mb Mb^T + Aext Bext^T + mu m1^T + m1 mu^T ; diag *= d2 ----------------
__global__ __launch_bounds__(256) void k_mm(const unsigned short* __restrict__ Mb,
                                            const unsigned short* __restrict__ Aext,
                                            const unsigned short* __restrict__ Bext,
                                            const float* __restrict__ mu,
                                            const float* __restrict__ m1,
                                            const float* __restrict__ d2,
                                            float* __restrict__ out) {
  __shared__ unsigned short As[128 * 64];
  __shared__ unsigned short Bs[128 * 64];
  int lid = blockIdx.y * 32 + blockIdx.x;
  int swz = (lid & 7) * 128 + (lid >> 3);  // 1024 % 8 == 0 -> bijective
  int i0 = (swz >> 5) * 128, j0 = (swz & 31) * 128;
  int tid = threadIdx.x, l = tid & 63, w = tid >> 6;
  int wr = w >> 1, wc = w & 1;
  f32x4 acc[4][4];
#pragma unroll
  for (int m = 0; m < 4; m++)
#pragma unroll
    for (int n = 0; n < 4; n++) acc[m][n] = (f32x4){0.f, 0.f, 0.f, 0.f};

  for (int k0 = 0; k0 < Nn; k0 += 64)
    mm_step(Mb, Nn, Mb, Nn, As, Bs, i0, j0, k0, l, w, wr, wc, acc);
  for (int k0 = 0; k0 < KEXT; k0 += 64)
    mm_step(Aext, KEXT, Bext, KEXT, As, Bs, i0, j0, k0, l, w, wr, wc, acc);

#pragma unroll
  for (int m = 0; m < 4; m++) {
#pragma unroll
    for (int n = 0; n < 4; n++) {
#pragma unroll
      for (int q = 0; q < 4; q++) {
        int gi = i0 + wr * 64 + m * 16 + ((l >> 4) << 2) + q;
        int gj = j0 + wc * 64 + n * 16 + (l & 15);
        float v = acc[m][n][q] + mu[gi] * m1[gj] + m1[gi] * mu[gj];
        if (gi == gj) v *= d2[gi];
        out[(size_t)gi * Nn + gj] = v;
      }
    }
  }
}

extern "C" void kernel_launch(void* const* d_in, const int* in_sizes, int n_in,
                              void* d_out, int out_size, void* d_ws, size_t ws_size,
                              hipStream_t stream) {
  const float* x = (const float*)d_in[0];  // [N,D]
  const float* w = (const float*)d_in[1];  // [D]
  const int* ei = (const int*)d_in[2];     // [2,E]
  const int* src = ei;
  const int* dstv = ei + Ee;
  float* out = (float*)d_out;

  // workspace (~71.4 MB)
  unsigned short* Mb = (unsigned short*)d_ws;                       // [4096][4096] bf16 (33.5MB)
  unsigned short* aext = Mb + (size_t)Nn * Nn;                      // [4096][1536] (12.6MB)
  unsigned short* bext = aext + (size_t)Nn * KEXT;                  // [4096][1536] (12.6MB)
  unsigned short* xb = bext + (size_t)Nn * KEXT;                    // [640][8192] (10.5MB)
  int2* ell = (int2*)(xb + (size_t)YC * XK);                        // WCAP*Nn (2MB)
  float* sq = (float*)(ell + (size_t)WCAP * Nn);                    // Nn
  float* dis = sq + Nn;                                             // Nn
  float* d2 = dis + Nn;                                             // Nn
  float* mu = d2 + Nn;                                              // Nn
  float* m1 = mu + Nn;                                              // Nn
  int* degi = (int*)(m1 + Nn);                                      // Nn -- zero block start
  int* degrow = degi + Nn;                                          // Nn
  int* slotcnt = degrow + Nn;                                       // Nn
  int* bincnt = slotcnt + Nn;                                       // WCAP+1 -- zero block end
  int* binbase = bincnt + (WCAP + 1);                               // WCAP+1
  int* perm = binbase + (WCAP + 1);                                 // Nn
  int* rnk = perm + Nn;                                             // Nn
  int* wsub = rnk + Nn;                                             // 64

  hipMemsetAsync(ell, 0, (size_t)WCAP * Nn * sizeof(int2), stream);
  hipMemsetAsync(degi, 0, sizeof(int) * (3 * Nn + (WCAP + 1)), stream);
  hipMemsetAsync(xb, 0, (size_t)YC * XK * sizeof(unsigned short), stream);

  k_sq<<<Nn, 256, 0, stream>>>(x, w, sq);
  k_count<<<Ee / 256, 256, 0, stream>>>(src, dstv, degi, degrow);
  k_dis<<<Nn / 256, 256, 0, stream>>>(degi, degrow, dis, d2);
  k_hist<<<1, 256, 0, stream>>>(degi, binbase);
  k_scatter<<<Nn / 256, 256, 0, stream>>>(degi, binbase, bincnt, perm, rnk);
  k_wsub<<<1, 64, 0, stream>>>(degi, perm, wsub);
  k_fill_ell<<<(Ee + Nn + 255) / 256, 256, 0, stream>>>(src, dstv, dis, rnk, slotcnt, ell);
  k_xpose<<<dim3(16, 128), 256, 0, stream>>>(x, xb);
  k_tail<<<Nn / 256, 256, 0, stream>>>(sq, xb);

  // M-pass: Mb = bf16(APPNP(I)), 8 packed bf16 columns per block
  k_appnp<<<Nn / CT8, TPB, Nn * sizeof(uint4), stream>>>(Mb, ell, perm, wsub);
  // Y = Mb * xb^T (hi+lo) ; epilogue builds aext/bext hi/lo splits + mu/m1
  k_ymm<<<dim3(YC / 128, Nn / 128), 256, 0, stream>>>(Mb, xb, w, aext, bext, mu, m1);
  // out = Mb Mb^T + Aext Bext^T + rank-2 ; diag *= d2
  k_mm<<<dim3(32, 32), 256, 0, stream>>>(Mb, aext, bext, mu, m1, d2, out);
}

// Round 9
// 865.786 us; speedup vs baseline: 1.6543x; 1.0299x over previous
//
#include <hip/hip_runtime.h>
#include <stdint.h>

#define Nn 4096
#define Dd 512
#define Ee 65536
#define HOPS 10
#define TPB 512
#define RPT (Nn / TPB)  // 8 rows per thread
#define CT8 8           // packed bf16 columns per block (8 x bf16 = 16B LDS entry)
#define WCAP 64         // ELL slot capacity (max in-degree+1; Poisson(16) max ~38)
#define KEXT 1536       // hi/lo-split extension K: [Phi|Phi|Plo] x [Yhi|Ylo|Yhi]
#define YC 640          // padded col count of Y = [X(512)|u|1|pad...]
#define XK 8192         // xb row length: [hi(4096) | lo(4096)]
#define NTMM 88         // k_mm2 K-tiles: 64 (Mb, K=4096) + 24 (ext, K=1536)

typedef short bf16x8 __attribute__((ext_vector_type(8)));
typedef float f32x4 __attribute__((ext_vector_type(4)));

// ---------------- helpers ----------------
__device__ __forceinline__ unsigned short bf16r(float x) {  // RNE fp32->bf16
  unsigned int b = __float_as_uint(x);
  return (unsigned short)((b + 0x7FFFu + ((b >> 16) & 1u)) >> 16);
}
__device__ __forceinline__ unsigned int pkbf(float lo, float hi) {  // 2 cols -> 1 uint
  return (unsigned int)bf16r(lo) | ((unsigned int)bf16r(hi) << 16);
}
__device__ __forceinline__ float ubf(unsigned short h) {
  return __uint_as_float(((unsigned int)h) << 16);
}
__device__ __forceinline__ void gld16(const unsigned short* g, unsigned short* lds) {
  __builtin_amdgcn_global_load_lds(
      (const __attribute__((address_space(1))) unsigned int*)g,
      (__attribute__((address_space(3))) unsigned int*)lds, 16, 0, 0);
}

// ---------------- sq[i] = sum_d w_d * x[i,d]^2 ----------------
__global__ __launch_bounds__(256) void k_sq(const float* __restrict__ x,
                                            const float* __restrict__ w,
                                            float* __restrict__ sq) {
  int row = blockIdx.x;
  int tid = threadIdx.x;
  const float* xr = x + (size_t)row * Dd;
  float partial = 0.f;
  for (int d = tid; d < Dd; d += 256) {
    float xv = xr[d];
    partial += xv * xv * w[d];
  }
  for (int off = 32; off >= 1; off >>= 1) partial += __shfl_down(partial, off, 64);
  __shared__ float red[4];
  int wv = tid >> 6, ln = tid & 63;
  if (ln == 0) red[wv] = partial;
  __syncthreads();
  if (tid == 0) sq[row] = red[0] + red[1] + red[2] + red[3];
}

// ---------------- degree counting ----------------
__global__ void k_count(const int* __restrict__ src, const int* __restrict__ dst,
                        int* __restrict__ degi, int* __restrict__ degrow) {
  int e = blockIdx.x * blockDim.x + threadIdx.x;
  if (e < Ee) {
    atomicAdd(&degi[dst[e]], 1);
    atomicAdd(&degrow[src[e]], 1);
  }
}

// ---------------- dis = (deg_in+1)^-0.5 ; d2 = 1/(deg_row+1) ----------------
__global__ void k_dis(const int* __restrict__ degi, const int* __restrict__ degrow,
                      float* __restrict__ dis, float* __restrict__ d2) {
  int i = blockIdx.x * 256 + threadIdx.x;
  dis[i] = rsqrtf((float)(degi[i] + 1));
  d2[i] = 1.0f / ((float)degrow[i] + 1.0f);
}

// ---------------- histogram of (deg_in+1) + exclusive prefix -> binbase ----------------
__global__ void k_hist(const int* __restrict__ degi, int* __restrict__ binbase) {
  __shared__ int h[WCAP + 1];
  int t = threadIdx.x;
  if (t <= WCAP) h[t] = 0;
  __syncthreads();
  for (int i = t; i < Nn; i += 256) {
    int d = degi[i] + 1;
    if (d > WCAP) d = WCAP;
    atomicAdd(&h[d], 1);
  }
  __syncthreads();
  if (t == 0) {
    int run = 0;
    for (int b = 0; b <= WCAP; b++) { int c = h[b]; binbase[b] = run; run += c; }
  }
}

// ---------------- counting-sort scatter: perm (sorted pos -> row), rnk (row -> pos) ----------------
__global__ void k_scatter(const int* __restrict__ degi, const int* __restrict__ binbase,
                          int* __restrict__ bincnt, int* __restrict__ perm,
                          int* __restrict__ rnk) {
  int i = blockIdx.x * 256 + threadIdx.x;
  int d = degi[i] + 1;
  if (d > WCAP) d = WCAP;
  int pos = binbase[d] + atomicAdd(&bincnt[d], 1);
  perm[pos] = i;
  rnk[i] = pos;
}

// ---------------- per-(wave,chain) slot bounds ----------------
__global__ void k_wsub(const int* __restrict__ degi, const int* __restrict__ perm,
                       int* __restrict__ wsub) {
  int t = threadIdx.x;
  int d = degi[perm[t * 64 + 63]] + 1;
  wsub[t] = d > WCAP ? WCAP : d;
}

// ---------------- ELL fill (slot-major, sorted-position indexed) ----------------
__global__ void k_fill_ell(const int* __restrict__ src, const int* __restrict__ dst,
                           const float* __restrict__ dis, const int* __restrict__ rnk,
                           int* __restrict__ slot, int2* __restrict__ ell) {
  int i = blockIdx.x * blockDim.x + threadIdx.x;
  if (i < Ee) {
    int s = src[i], d = dst[i];
    int p = atomicAdd(&slot[d], 1);
    if (p < WCAP) ell[(size_t)p * Nn + rnk[d]] = make_int2(s, __float_as_int(dis[s] * dis[d]));
  } else if (i < Ee + Nn) {
    int v = i - Ee;
    int p = atomicAdd(&slot[v], 1);
    if (p < WCAP) ell[(size_t)p * Nn + rnk[v]] = make_int2(v, __float_as_int(dis[v] * dis[v]));
  }
}

// ---------------- xb[c][k] = bf16 hi/lo of X^T: rows c = feature cols, k = nodes ----------------
__global__ __launch_bounds__(256) void k_xpose(const float* __restrict__ x,
                                               unsigned short* __restrict__ xb) {
  __shared__ float tile[32][33];
  int cx = blockIdx.x, rx = blockIdx.y;
  int t = threadIdx.x, txc = t & 31, tyc = t >> 5;
#pragma unroll
  for (int i = 0; i < 4; i++) {
    int a = tyc + i * 8;
    tile[a][txc] = x[(size_t)(rx * 32 + a) * Dd + cx * 32 + txc];
  }
  __syncthreads();
#pragma unroll
  for (int i = 0; i < 4; i++) {
    int a = tyc + i * 8;
    int c = cx * 32 + a;
    float v = tile[txc][a];
    unsigned short hi = bf16r(v);
    xb[(size_t)c * XK + rx * 32 + txc] = hi;
    xb[(size_t)c * XK + Nn + rx * 32 + txc] = bf16r(v - ubf(hi));
  }
}

// ---------------- xb tail rows: u (=sq) at c=512, ones at c=513 ----------------
__global__ void k_tail(const float* __restrict__ sq, unsigned short* __restrict__ xb) {
  int r = blockIdx.x * 256 + threadIdx.x;
  float v = sq[r];
  unsigned short hi = bf16r(v);
  xb[(size_t)512 * XK + r] = hi;
  xb[(size_t)512 * XK + Nn + r] = bf16r(v - ubf(hi));
  xb[(size_t)513 * XK + r] = bf16r(1.0f);
  xb[(size_t)513 * XK + Nn + r] = 0;
}

// ---------------- fused 10-hop APPNP(I) -> Mb = bf16(M); h packed bf16x8 in LDS ----------------
__global__ __launch_bounds__(TPB, 4) void k_appnp(unsigned short* __restrict__ mb,
                                                  const int2* __restrict__ ell,
                                                  const int* __restrict__ perm,
                                                  const int* __restrict__ wsub) {
  extern __shared__ uint4 h4u[];  // Nn entries = 64 KB (8 bf16 cols packed)
  int j0 = blockIdx.x * CT8;
  int tid = threadIdx.x;
  int wv = tid >> 6, ln = tid & 63;
  int qb = wv * 512 + ln;

  // init h = identity columns j0..j0+7 (bf16(1.0) = 0x3F80 in the matching half-word)
#pragma unroll
  for (int rr = 0; rr < RPT; rr++) {
    int r = tid + rr * TPB;
    uint4 v = make_uint4(0u, 0u, 0u, 0u);
    int c = r - j0;
    if (c >= 0 && c < 8) {
      unsigned int one = (c & 1) ? 0x3F800000u : 0x00003F80u;
      if ((c >> 1) == 0) v.x = one;
      else if ((c >> 1) == 1) v.y = one;
      else if ((c >> 1) == 2) v.z = one;
      else v.w = one;
    }
    h4u[r] = v;
  }

  int ws[RPT];
#pragma unroll
  for (int rr = 0; rr < RPT; rr++)
    ws[rr] = __builtin_amdgcn_readfirstlane(wsub[wv * 8 + rr]);
  const int Wv = ws[RPT - 1];

  int rp[RPT], x0c[RPT];
#pragma unroll
  for (int rr = 0; rr < RPT; rr++) {
    rp[rr] = perm[qb + rr * 64];
    int c = rp[rr] - j0;
    x0c[rr] = (c >= 0 && c < 8) ? c : -1;
  }
  __syncthreads();

  for (int it = 0; it < HOPS; it++) {
    int2 cur[RPT];
#pragma unroll
    for (int rr = 0; rr < RPT; rr++) cur[rr] = ell[qb + rr * 64];
    float acc[RPT][8];
#pragma unroll
    for (int rr = 0; rr < RPT; rr++)
#pragma unroll
      for (int c = 0; c < 8; c++) acc[rr][c] = (x0c[rr] == c) ? 1.0f : 0.0f;
    for (int s = 0; s < Wv; s++) {
      int sn = s + 1;
      int2 nxt[RPT];
#pragma unroll
      for (int rr = 0; rr < RPT; rr++)
        if (sn < ws[rr]) nxt[rr] = ell[(size_t)sn * Nn + qb + rr * 64];
#pragma unroll
      for (int rr = 0; rr < RPT; rr++)
        if (s < ws[rr]) {
          float vv = __int_as_float(cur[rr].y);
          uint4 hu = h4u[cur[rr].x];
          acc[rr][0] = fmaf(vv, __uint_as_float(hu.x << 16), acc[rr][0]);
          acc[rr][1] = fmaf(vv, __uint_as_float(hu.x & 0xFFFF0000u), acc[rr][1]);
          acc[rr][2] = fmaf(vv, __uint_as_float(hu.y << 16), acc[rr][2]);
          acc[rr][3] = fmaf(vv, __uint_as_float(hu.y & 0xFFFF0000u), acc[rr][3]);
          acc[rr][4] = fmaf(vv, __uint_as_float(hu.z << 16), acc[rr][4]);
          acc[rr][5] = fmaf(vv, __uint_as_float(hu.z & 0xFFFF0000u), acc[rr][5]);
          acc[rr][6] = fmaf(vv, __uint_as_float(hu.w << 16), acc[rr][6]);
          acc[rr][7] = fmaf(vv, __uint_as_float(hu.w & 0xFFFF0000u), acc[rr][7]);
        }
#pragma unroll
      for (int rr = 0; rr < RPT; rr++)
        if (sn < ws[rr]) cur[rr] = nxt[rr];
    }
    __syncthreads();
#pragma unroll
    for (int rr = 0; rr < RPT; rr++) {
      uint4 v;
      v.x = pkbf(0.5f * acc[rr][0], 0.5f * acc[rr][1]);
      v.y = pkbf(0.5f * acc[rr][2], 0.5f * acc[rr][3]);
      v.z = pkbf(0.5f * acc[rr][4], 0.5f * acc[rr][5]);
      v.w = pkbf(0.5f * acc[rr][6], 0.5f * acc[rr][7]);
      h4u[rp[rr]] = v;
    }
    __syncthreads();
  }

#pragma unroll
  for (int rr = 0; rr < RPT; rr++) {
    int r = tid + rr * TPB;
    *(uint4*)&mb[(size_t)r * Nn + j0] = h4u[r];
  }
}

// ---------------- 128^2 MFMA tile step (proven; used by k_ymm) ----------------
__device__ __forceinline__ void mm_step(const unsigned short* __restrict__ Ap, int lda,
                                        const unsigned short* __restrict__ Bp, int ldb,
                                        unsigned short* As, unsigned short* Bs,
                                        int i0, int j0, int k0, int l, int w, int wr,
                                        int wc, f32x4 acc[4][4]) {
  int rsub = w * 8 + (l >> 3);              // row within 32-row round
  int scg = ((l & 7) ^ (l >> 3)) * 8;       // pre-swizzled source chunk offset (ushorts)
#pragma unroll
  for (int r = 0; r < 4; r++) {
    int row = r * 32 + rsub;
    gld16(Ap + (size_t)(i0 + row) * lda + k0 + scg, As + (r * 32 + w * 8) * 64);
    gld16(Bp + (size_t)(j0 + row) * ldb + k0 + scg, Bs + (r * 32 + w * 8) * 64);
  }
  __syncthreads();
#pragma unroll
  for (int q = 0; q < 2; q++) {
    bf16x8 af[4], bg[4];
#pragma unroll
    for (int m = 0; m < 4; m++) {
      int ar = wr * 64 + m * 16 + (l & 15);
      af[m] = *(const bf16x8*)(As + ar * 64 + ((((l >> 4) + 4 * q) ^ (ar & 7)) * 8));
      int br = wc * 64 + m * 16 + (l & 15);
      bg[m] = *(const bf16x8*)(Bs + br * 64 + ((((l >> 4) + 4 * q) ^ (br & 7)) * 8));
    }
#pragma unroll
    for (int m = 0; m < 4; m++)
#pragma unroll
      for (int n = 0; n < 4; n++)
        acc[m][n] = __builtin_amdgcn_mfma_f32_16x16x32_bf16(af[m], bg[n], acc[m][n], 0, 0, 0);
  }
  __syncthreads();
}

// ---------------- Y = Mb * xb^T (K = 4096 hi + 4096 lo); epilogue -> aext/bext/mu/m1 ----------------
__global__ __launch_bounds__(256) void k_ymm(const unsigned short* __restrict__ Mb,
                                             const unsigned short* __restrict__ xb,
                                             const float* __restrict__ wp,
                                             unsigned short* __restrict__ aext,
                                             unsigned short* __restrict__ bext,
                                             float* __restrict__ mu,
                                             float* __restrict__ m1) {
  __shared__ unsigned short As[128 * 64];
  __shared__ unsigned short Bs[128 * 64];
  int i0 = blockIdx.y * 128, j0 = blockIdx.x * 128;
  int tid = threadIdx.x, l = tid & 63, w = tid >> 6;
  int wr = w >> 1, wc = w & 1;
  f32x4 acc[4][4];
#pragma unroll
  for (int m = 0; m < 4; m++)
#pragma unroll
    for (int n = 0; n < 4; n++) acc[m][n] = (f32x4){0.f, 0.f, 0.f, 0.f};

  for (int k0 = 0; k0 < Nn; k0 += 64)
    mm_step(Mb, Nn, xb, XK, As, Bs, i0, j0, k0, l, w, wr, wc, acc);
  for (int k0 = 0; k0 < Nn; k0 += 64)
    mm_step(Mb, Nn, xb + Nn, XK, As, Bs, i0, j0, k0, l, w, wr, wc, acc);

#pragma unroll
  for (int m = 0; m < 4; m++) {
#pragma unroll
    for (int n = 0; n < 4; n++) {
#pragma unroll
      for (int q = 0; q < 4; q++) {
        int gi = i0 + wr * 64 + m * 16 + ((l >> 4) << 2) + q;
        int gj = j0 + wc * 64 + n * 16 + (l & 15);
        float y = acc[m][n][q];
        if (gj < 512) {
          unsigned short yhi = bf16r(y);
          unsigned short ylo = bf16r(y - ubf(yhi));
          float p = -2.f * wp[gj] * y;
          unsigned short phi = bf16r(p);
          unsigned short plo = bf16r(p - ubf(phi));
          bext[(size_t)gi * KEXT + gj] = yhi;
          bext[(size_t)gi * KEXT + 512 + gj] = ylo;
          bext[(size_t)gi * KEXT + 1024 + gj] = yhi;
          aext[(size_t)gi * KEXT + gj] = phi;
          aext[(size_t)gi * KEXT + 512 + gj] = phi;
          aext[(size_t)gi * KEXT + 1024 + gj] = plo;
        } else if (gj == 512) {
          mu[gi] = y;
        } else if (gj == 513) {
          m1[gi] = y;
        }
      }
    }
  }
}

// ---------------- 8-phase 256^2 GEMM: out = Mb Mb^T + Aext Bext^T + rank2, diag*d2 ----------
// 8 waves (2Mx4N), per-wave 128x64 output, BK=64, LDS dbuf 128KB, raw s_barrier (no drain),
// per-phase {12 ds_read | staging gld16 | 16 MFMA with setprio}. Each wave stages exactly
// the A-half (wr) and B-half (wc>>1) it consumes. One vmcnt(0) per K-tile, issued >=2
// phases after the newest staging gld -> near-free. Chunk XOR swizzle as in mm_step.
__global__ __launch_bounds__(512, 2) void k_mm2(const unsigned short* __restrict__ Mb,
                                                const unsigned short* __restrict__ Aext,
                                                const unsigned short* __restrict__ Bext,
                                                const float* __restrict__ mu,
                                                const float* __restrict__ m1,
                                                const float* __restrict__ d2,
                                                float* __restrict__ out) {
  extern __shared__ unsigned short sh[];  // [A0|A1|B0|B1], each 256*64 ushort = 32 KB
  int lid = blockIdx.x;
  int swz = (lid & 7) * 32 + (lid >> 3);  // 256 % 8 == 0 -> bijective XCD swizzle
  int i0 = (swz >> 4) * 256, j0 = (swz & 15) * 256;
  int tid = threadIdx.x, l = tid & 63, w = tid >> 6;
  int wr = w >> 2, wc = w & 3;
  int rsub = l >> 3;
  int scg = ((l & 7) ^ (l >> 3)) * 8;          // pre-swizzled source chunk (ushorts)
  int aRowBase = wr * 128 + wc * 32;           // wave's A staging rows
  int bRowBase = (wc >> 1) * 128 + (wr * 2 + (wc & 1)) * 32;  // wave's B staging rows

  f32x4 acc[8][4];
#pragma unroll
  for (int m = 0; m < 8; m++)
#pragma unroll
    for (int n = 0; n < 4; n++) acc[m][n] = (f32x4){0.f, 0.f, 0.f, 0.f};

  auto STG = [&](int g, int t, int b) {  // g 0-3: B stage s=g ; g 4-7: A stage s=g-4
    const unsigned short *pa, *pb;
    int lda, kk;
    if (t < 64) { pa = Mb; pb = Mb; lda = Nn; kk = t * 64; }
    else { pa = Aext; pb = Bext; lda = KEXT; kk = (t - 64) * 64; }
    if (g < 4) {
      int r = bRowBase + g * 8;
      gld16(pb + (size_t)(j0 + r + rsub) * lda + kk + scg, sh + 32768 + b * 16384 + r * 64);
    } else {
      int r = aRowBase + (g - 4) * 8;
      gld16(pa + (size_t)(i0 + r + rsub) * lda + kk + scg, sh + b * 16384 + r * 64);
    }
  };

  // prologue: stage tile 0 into buf 0, drain, barrier
#pragma unroll
  for (int g = 0; g < 8; g++) STG(g, 0, 0);
  asm volatile("s_waitcnt vmcnt(0)" ::: "memory");
  __builtin_amdgcn_s_barrier();

  for (int kt = 0; kt < NTMM; kt++) {
    int cur = kt & 1, nxtb = cur ^ 1;
    const unsigned short* Ac = sh + cur * 16384;
    const unsigned short* Bc = sh + 32768 + cur * 16384;
    bool pre = (kt + 1 < NTMM);
#pragma unroll
    for (int p = 0; p < 4; p++) {
      const int mh = p >> 1, nh = p & 1;
      bf16x8 af[4][2], bg[2][2];
#pragma unroll
      for (int m4 = 0; m4 < 4; m4++) {
        int ar = wr * 128 + (mh * 4 + m4) * 16 + (l & 15);
#pragma unroll
        for (int ks = 0; ks < 2; ks++) {
          int c = ks * 4 + (l >> 4);
          af[m4][ks] = *(const bf16x8*)(Ac + ar * 64 + ((c ^ (ar & 7)) * 8));
        }
      }
#pragma unroll
      for (int n2 = 0; n2 < 2; n2++) {
        int br = wc * 64 + (nh * 2 + n2) * 16 + (l & 15);
#pragma unroll
        for (int ks = 0; ks < 2; ks++) {
          int c = ks * 4 + (l >> 4);
          bg[n2][ks] = *(const bf16x8*)(Bc + br * 64 + ((c ^ (br & 7)) * 8));
        }
      }
      if (pre) {
        if (p == 0) { STG(0, kt + 1, nxtb); STG(1, kt + 1, nxtb); STG(2, kt + 1, nxtb); }
        else if (p == 1) { STG(3, kt + 1, nxtb); STG(4, kt + 1, nxtb); STG(5, kt + 1, nxtb); }
        else if (p == 2) { STG(6, kt + 1, nxtb); STG(7, kt + 1, nxtb); }
      }
      if (p == 3) asm volatile("s_waitcnt vmcnt(0)" ::: "memory");
      __builtin_amdgcn_s_barrier();
      __builtin_amdgcn_s_setprio(1);
#pragma unroll
      for (int m4 = 0; m4 < 4; m4++)
#pragma unroll
        for (int n2 = 0; n2 < 2; n2++)
#pragma unroll
          for (int ks = 0; ks < 2; ks++)
            acc[mh * 4 + m4][nh * 2 + n2] = __builtin_amdgcn_mfma_f32_16x16x32_bf16(
                af[m4][ks], bg[n2][ks], acc[mh * 4 + m4][nh * 2 + n2], 0, 0, 0);
      __builtin_amdgcn_s_setprio(0);
      __builtin_amdgcn_s_barrier();
    }
  }

#pragma unroll
  for (int m = 0; m < 8; m++) {
#pragma unroll
    for (int n = 0; n < 4; n++) {
#pragma unroll
      for (int q = 0; q < 4; q++) {
        int gi = i0 + wr * 128 + m * 16 + ((l >> 4) << 2) + q;
        int gj = j0 + wc * 64 + n * 16 + (l & 15);
        float v = acc[m][n][q] + mu[gi] * m1[gj] + m1[gi] * mu[gj];
        if (gi == gj) v *= d2[gi];
        out[(size_t)gi * Nn + gj] = v;
      }
    }
  }
}

extern "C" void kernel_launch(void* const* d_in, const int* in_sizes, int n_in,
                              void* d_out, int out_size, void* d_ws, size_t ws_size,
                              hipStream_t stream) {
  const float* x = (const float*)d_in[0];  // [N,D]
  const float* w = (const float*)d_in[1];  // [D]
  const int* ei = (const int*)d_in[2];     // [2,E]
  const int* src = ei;
  const int* dstv = ei + Ee;
  float* out = (float*)d_out;

  // workspace (~71.4 MB)
  unsigned short* Mb = (unsigned short*)d_ws;                       // [4096][4096] bf16 (33.5MB)
  unsigned short* aext = Mb + (size_t)Nn * Nn;                      // [4096][1536] (12.6MB)
  unsigned short* bext = aext + (size_t)Nn * KEXT;                  // [4096][1536] (12.6MB)
  unsigned short* xb = bext + (size_t)Nn * KEXT;                    // [640][8192] (10.5MB)
  int2* ell = (int2*)(xb + (size_t)YC * XK);                        // WCAP*Nn (2MB)
  float* sq = (float*)(ell + (size_t)WCAP * Nn);                    // Nn
  float* dis = sq + Nn;                                             // Nn
  float* d2 = dis + Nn;                                             // Nn
  float* mu = d2 + Nn;                                              // Nn
  float* m1 = mu + Nn;                                              // Nn
  int* degi = (int*)(m1 + Nn);                                      // Nn -- zero block start
  int* degrow = degi + Nn;                                          // Nn
  int* slotcnt = degrow + Nn;                                       // Nn
  int* bincnt = slotcnt + Nn;                                       // WCAP+1 -- zero block end
  int* binbase = bincnt + (WCAP + 1);                               // WCAP+1
  int* perm = binbase + (WCAP + 1);                                 // Nn
  int* rnk = perm + Nn;                                             // Nn
  int* wsub = rnk + Nn;                                             // 64

  hipMemsetAsync(ell, 0, (size_t)WCAP * Nn * sizeof(int2), stream);
  hipMemsetAsync(degi, 0, sizeof(int) * (3 * Nn + (WCAP + 1)), stream);
  hipMemsetAsync(xb, 0, (size_t)YC * XK * sizeof(unsigned short), stream);

  k_sq<<<Nn, 256, 0, stream>>>(x, w, sq);
  k_count<<<Ee / 256, 256, 0, stream>>>(src, dstv, degi, degrow);
  k_dis<<<Nn / 256, 256, 0, stream>>>(degi, degrow, dis, d2);
  k_hist<<<1, 256, 0, stream>>>(degi, binbase);
  k_scatter<<<Nn / 256, 256, 0, stream>>>(degi, binbase, bincnt, perm, rnk);
  k_wsub<<<1, 64, 0, stream>>>(degi, perm, wsub);
  k_fill_ell<<<(Ee + Nn + 255) / 256, 256, 0, stream>>>(src, dstv, dis, rnk, slotcnt, ell);
  k_xpose<<<dim3(16, 128), 256, 0, stream>>>(x, xb);
  k_tail<<<Nn / 256, 256, 0, stream>>>(sq, xb);

  // M-pass: Mb = bf16(APPNP(I)), 8 packed bf16 columns per block
  k_appnp<<<Nn / CT8, TPB, Nn * sizeof(uint4), stream>>>(Mb, ell, perm, wsub);
  // Y = Mb * xb^T (hi+lo) ; epilogue builds aext/bext hi/lo splits + mu/m1
  k_ymm<<<dim3(YC / 128, Nn / 128), 256, 0, stream>>>(Mb, xb, w, aext, bext, mu, m1);
  // out = Mb Mb^T + Aext Bext^T + rank-2 ; diag *= d2  (8-phase 256^2)
  k_mm2<<<256, 512, 131072, stream>>>(Mb, aext, bext, mu, m1, d2, out);
}